// Round 11
// baseline (426.259 us; speedup 1.0000x reference)
//
#include <hip/hip_runtime.h>
#include <cstdint>
#include <cstddef>

typedef unsigned short u16;
typedef unsigned int uint;
typedef __bf16 bf16x8 __attribute__((ext_vector_type(8)));
typedef float f32x4 __attribute__((ext_vector_type(4)));

#define BATCH 2
#define SEQ 2048
#define DIM 1024
#define NH 16
#define DH 64
#define FFD 4096
#define MROWS 4096            // BATCH*SEQ
#define PER_BATCH 2097152     // SEQ*DIM

__device__ __forceinline__ u16 f2b(float f) {
  uint u = __builtin_bit_cast(uint, f);
  u += 0x7FFFu + ((u >> 16) & 1u);   // RNE
  return (u16)(u >> 16);
}

// pack 2 floats -> 2 bf16 in one u32; native casts are RNE (identical to f2b)
__device__ __forceinline__ uint pkbf2(float a, float b) {
  u16 x = __builtin_bit_cast(u16, (__bf16)a);
  u16 y = __builtin_bit_cast(u16, (__bf16)b);
  return (uint)x | ((uint)y << 16);
}

// XCD-aware bijective block swizzle (requires nwg % 8 == 0 — true here).
__device__ __forceinline__ int xcd_swz(int flat, int nwg) {
  return (flat & 7) * (nwg >> 3) + (flat >> 3);
}

// async global->LDS, 16B per lane; LDS dest is wave-uniform base + lane*16
#define GLL(gp, lp)                                                            \
  __builtin_amdgcn_global_load_lds(                                            \
      (const __attribute__((address_space(1))) void*)(gp),                     \
      (__attribute__((address_space(3))) void*)(lp), 16, 0, 0)

// ---------------------------------------------------------------- elementwise
__global__ __launch_bounds__(256) void cvt4_kernel(const float* __restrict__ s0,
                                                   const float* __restrict__ s1,
                                                   const float* __restrict__ s2,
                                                   const float* __restrict__ s3,
                                                   u16* d0, u16* d1, u16* d2, u16* d3,
                                                   int n) {
  int t = blockIdx.y;
  const float* src = (t == 0) ? s0 : (t == 1) ? s1 : (t == 2) ? s2 : s3;
  u16* dst = (t == 0) ? d0 : (t == 1) ? d1 : (t == 2) ? d2 : d3;
  int i = (blockIdx.x * 256 + threadIdx.x) * 8;
  if (i >= n) return;
  float4 a = *(const float4*)(src + i);
  float4 b = *(const float4*)(src + i + 4);
  uint4 o;
  o.x = f2b(a.x) | ((uint)f2b(a.y) << 16);
  o.y = f2b(a.z) | ((uint)f2b(a.w) << 16);
  o.z = f2b(b.x) | ((uint)f2b(b.y) << 16);
  o.w = f2b(b.z) | ((uint)f2b(b.w) << 16);
  *(uint4*)(dst + i) = o;
}

__global__ __launch_bounds__(256) void reduce_stats_kernel(const float* __restrict__ x,
                                                           float* __restrict__ stats) {
  int b = blockIdx.y;
  const float* p = x + (size_t)b * PER_BATCH;
  float s = 0.f, ss = 0.f;
  int stride = gridDim.x * 256 * 4;
  for (int i = (blockIdx.x * 256 + threadIdx.x) * 4; i < PER_BATCH; i += stride) {
    float4 v = *(const float4*)(p + i);
    s  += (v.x + v.y) + (v.z + v.w);
    ss += (v.x * v.x + v.y * v.y) + (v.z * v.z + v.w * v.w);
  }
#pragma unroll
  for (int m = 32; m; m >>= 1) { s += __shfl_xor(s, m); ss += __shfl_xor(ss, m); }
  __shared__ float red[16];
  int w = threadIdx.x >> 6;
  if ((threadIdx.x & 63) == 0) { red[w] = s; red[8 + w] = ss; }
  __syncthreads();
  if (threadIdx.x == 0) {
    atomicAdd(&stats[b * 2],     red[0] + red[1] + red[2] + red[3]);
    atomicAdd(&stats[b * 2 + 1], red[8] + red[9] + red[10] + red[11]);
  }
}

__global__ __launch_bounds__(256) void ln_apply_kernel(const float* __restrict__ xin,
                                                       const float* __restrict__ stats,
                                                       u16* __restrict__ out) {
  int i = (blockIdx.x * 256 + threadIdx.x) * 4;
  int b = i >> 21;   // i / PER_BATCH
  const float inv = 1.f / (float)PER_BATCH;
  float mu = stats[b * 2] * inv;
  float var = stats[b * 2 + 1] * inv - mu * mu;
  float rs = rsqrtf(var + 1e-5f);
  float4 v = *(const float4*)(xin + i);
  uint r0 = f2b((v.x - mu) * rs) | ((uint)f2b((v.y - mu) * rs) << 16);
  uint r1 = f2b((v.z - mu) * rs) | ((uint)f2b((v.w - mu) * rs) << 16);
  *(uint2*)(out + i) = make_uint2(r0, r1);
}

// ---------------------------------------------------------------- GEMM (C = A * B^T)
// m97 structure + 16B-granule XOR swizzle on LDS tiles:
//   phys chunk = c_log ^ (row & 7); GLL source chunk scl = (lane&7)^(lane>>3)
//   keeps the DMA lane-linear. Frag-read chunk offset ((kk*4+qd)^(ln&7)) is
//   loop-invariant.
// STRUCTURE LESSONS (R3-R10):
//   - 2-phase 4-wave blocks plateau at MfmaUtil ~22%; TN=64 triple-buf
//     counted vmcnt(6) recovers ~5% (R9). 8-wave 256^2 exits the plateau
//     (R6 FFN-1 ~1.7x) but needs a full grid (R8: 192 blocks neutral).
//   - ATOMIC split-K epilogue NOT viable (R7: 64MB RMW serializes at L2).
//   - attn: QBLK=64 for occupancy REGRESSED (R10) — per-tile K/V fragment
//     reads stop amortizing; attn is overhead-bound, not occupancy-bound.
// STATS: fuse LayerNorm sum/sumsq into the fp32 epilogue (wave-shuffle
//   reduce + 2 atomicAdds/wave; blocks never straddle the batch boundary).
template <int TN, int RELU, int RESID, int OUTBF, int TRV, int DBUF, int STATS>
__device__ __forceinline__ void gemm_bt_body(const u16* __restrict__ A,
                                             const u16* __restrict__ Bm,
                                             const float* __restrict__ bias,
                                             const float* __restrict__ resid,
                                             void* __restrict__ Cout,
                                             float* __restrict__ stats,
                                             int M, int N, int K,
                                             int m0, int n0, float oscale) {
  constexpr int AI  = (TN == 128) ? 4 : 2;   // 16-row acc tiles per wave
  constexpr int BCH = (TN == 128) ? 4 : 2;   // B staging chunks per wave
  constexpr int NB  = DBUF ? 3 : 1;          // LDS buffers (3 = counted pipeline)
  __shared__ __align__(16) u16 As[NB][128 * 64];
  __shared__ __align__(16) u16 Bs[NB][TN * 64];
  const int tid = threadIdx.x;
  const int lane = tid & 63, w = tid >> 6;
  const int wr = (TN == 128) ? (w >> 1) : w;
  const int wc = (TN == 128) ? (w & 1) : 0;
  const int ln = lane & 15, qd = lane >> 4;

  f32x4 acc[AI][4] = {};

  const int lrow = lane >> 3;
  const int scl  = (lane & 7) ^ lrow;        // swizzled logical chunk
  const u16* Ag = A  + (size_t)(m0 + w * 32 + lrow) * K + scl * 8;
  const u16* Bg = Bm + (size_t)(n0 + w * 8 * BCH + lrow) * K + scl * 8;

  const int co0 = ((qd)     ^ (ln & 7)) * 8;
  const int co1 = ((4 + qd) ^ (ln & 7)) * 8;

  auto STAGE = [&](int buf, int k0) {
#pragma unroll
    for (int r = 0; r < 4; ++r)
      GLL(Ag + (size_t)(r * 8) * K + k0, As[buf] + (w * 4 + r) * 512);
#pragma unroll
    for (int r = 0; r < BCH; ++r)
      GLL(Bg + (size_t)(r * 8) * K + k0, Bs[buf] + (w * BCH + r) * 512);
  };

  auto COMPUTE = [&](int buf) {
#pragma unroll
    for (int kk = 0; kk < 2; ++kk) {
      const int co = kk ? co1 : co0;
      bf16x8 af[AI], bf[4];
#pragma unroll
      for (int t = 0; t < AI; ++t)
        af[t] = *(const bf16x8*)&As[buf][(wr * (AI * 16) + t * 16 + ln) * 64 + co];
#pragma unroll
      for (int t = 0; t < 4; ++t)
        bf[t] = *(const bf16x8*)&Bs[buf][(wc * 64 + t * 16 + ln) * 64 + co];
#pragma unroll
      for (int i = 0; i < AI; ++i)
#pragma unroll
        for (int j = 0; j < 4; ++j)
          acc[i][j] = __builtin_amdgcn_mfma_f32_16x16x32_bf16(af[i], bf[j], acc[i][j], 0, 0, 0);
    }
  };

  if constexpr (NB == 3) {
    // depth-2 counted pipeline: 6 GLLs per wave per STAGE (T4: never drain
    // vmcnt to 0 in the loop). Hazard: buffer (t+2)%3 was last read in
    // COMPUTE(t-1) whose ds_reads retire before any wave passes barrier t.
    const int nk = K >> 6;
    STAGE(0, 0);
    STAGE(1, 64);
    int c = 0, s = 2;
    int t = 0;
    for (; t + 1 < nk; ++t) {
      asm volatile("s_waitcnt vmcnt(6)" ::: "memory");
      __builtin_amdgcn_s_barrier();
      __builtin_amdgcn_sched_barrier(0);
      if (t + 2 < nk) STAGE(s, (t + 2) * 64);
      COMPUTE(c);
      c = (c == 2) ? 0 : c + 1;
      s = (s == 2) ? 0 : s + 1;
    }
    asm volatile("s_waitcnt vmcnt(0)" ::: "memory");
    __builtin_amdgcn_s_barrier();
    __builtin_amdgcn_sched_barrier(0);
    COMPUTE(c);
  } else {
    for (int k0 = 0; k0 < K; k0 += 64) {
      __syncthreads();
      STAGE(0, k0);
      __syncthreads();
      COMPUTE(0);
    }
  }

  float sum = 0.f, ssum = 0.f;   // LN stats (STATS path)

#pragma unroll
  for (int i = 0; i < AI; ++i) {
    int row = m0 + wr * (AI * 16) + i * 16 + qd * 4;
#pragma unroll
    for (int j = 0; j < 4; ++j) {
      int col = n0 + wc * 64 + j * 16 + ln;
      float bv = bias[col];
      if (TRV) {
        // transposed bf16 store: vT[col][row..row+3] as one 8B write
        union { uint2 u2; u16 us[4]; } pk;
#pragma unroll
        for (int r = 0; r < 4; ++r) pk.us[r] = f2b(acc[i][j][r] + bv);
        *(uint2*)&((u16*)Cout)[(size_t)col * MROWS + row] = pk.u2;
      } else {
#pragma unroll
        for (int r = 0; r < 4; ++r) {
          float v = (acc[i][j][r] + bv) * oscale;
          if (RELU) v = fmaxf(v, 0.f);
          size_t off = (size_t)(row + r) * N + col;
          if (RESID) v += resid[off];
          if (OUTBF) ((u16*)Cout)[off] = f2b(v);
          else       ((float*)Cout)[off] = v;
          if (STATS) { sum += v; ssum += v * v; }
        }
      }
    }
  }

  if (STATS) {
    // all of this block's rows are in one batch (128 | 2048)
#pragma unroll
    for (int m = 32; m; m >>= 1) { sum += __shfl_xor(sum, m); ssum += __shfl_xor(ssum, m); }
    if (lane == 0) {
      int b = m0 >> 11;   // row / SEQ
      atomicAdd(&stats[b * 2], sum);
      atomicAdd(&stats[b * 2 + 1], ssum);
    }
  }
}

template <int TN, int RELU, int RESID, int OUTBF, int DBUF, int STATS>
__global__ __launch_bounds__(256) void gemm_bt_kernel(const u16* __restrict__ A,
                                                      const u16* __restrict__ Bm,
                                                      const float* __restrict__ bias,
                                                      const float* __restrict__ resid,
                                                      void* __restrict__ Cout,
                                                      float* __restrict__ stats,
                                                      int M, int N, int K) {
  const int nx = gridDim.x;
  const int nwg = nx * gridDim.y;
  const int wid = xcd_swz(blockIdx.x + nx * blockIdx.y, nwg);
  gemm_bt_body<TN, RELU, RESID, OUTBF, 0, DBUF, STATS>(A, Bm, bias, resid, Cout, stats,
                                                       M, N, K,
                                                       (wid / nx) * 128, (wid % nx) * TN, 1.0f);
}

// fused QKV on the R9-proven TN=64 triple-buf structure: per proj 512 blocks
// (16 N-tiles x 32 M-tiles), z selects projection; 72 KB LDS -> 2 blocks/CU.
// V (z==2) writes transposed vT; Q (z==0) pre-scaled by 0.25 (ref's bug).
__global__ __launch_bounds__(256) void gemm_qkv_kernel(const u16* __restrict__ A,
                                                       const u16* B0, const u16* B1, const u16* B2,
                                                       const float* c0, const float* c1, const float* c2,
                                                       u16* o0, u16* o1, u16* o2) {
  int z = blockIdx.z;
  const int wid = xcd_swz(blockIdx.x + 16 * blockIdx.y, 512);
  const int m0 = (wid >> 4) * 128, n0 = (wid & 15) * 64;
  if (z == 2) {
    gemm_bt_body<64, 0, 0, 1, 1, 1, 0>(A, B2, c2, nullptr, o2, nullptr,
                                       MROWS, DIM, DIM, m0, n0, 1.0f);
  } else {
    const u16* Bm = (z == 0) ? B0 : B1;
    const float* bias = (z == 0) ? c0 : c1;
    u16* Cout = (z == 0) ? o0 : o1;
    float sc = (z == 0) ? 0.25f : 1.0f;
    gemm_bt_body<64, 0, 0, 1, 0, 1, 0>(A, Bm, bias, nullptr, Cout, nullptr,
                                       MROWS, DIM, DIM, m0, n0, sc);
  }
}

// ---------------------------------------------------------------- 256x256 GEMM
// 8-wave (512-thread) 256x256 tile, BK=64, wave tile 128x64 (2M x 4N).
// Exits the 4-wave 2-phase plateau (R6: FFN-1 ~1.7x). Single-barrier
// ping-pong dbuf (128 KB LDS, 1 block/CU of 8 waves) — depth-1 suffices:
// COMPUTE (~2000cy) >> GLL latency.
template <int RELU>
__global__ __launch_bounds__(512, 2) void gemm256_kernel(const u16* __restrict__ A,
                                                         const u16* __restrict__ Bm,
                                                         const float* __restrict__ bias,
                                                         u16* __restrict__ Cout,
                                                         int M, int N, int K) {
  __shared__ __align__(16) u16 As[2][256 * 64];   // 32 KB x2
  __shared__ __align__(16) u16 Bs[2][256 * 64];   // 32 KB x2  (total 128 KB)
  const int tid = threadIdx.x;
  const int lane = tid & 63, w = tid >> 6;        // 8 waves
  const int wr = w >> 2, wc = w & 3;              // 2M x 4N
  const int ln = lane & 15, qd = lane >> 4;

  const int nx = gridDim.x;
  const int nwg = nx * gridDim.y;
  const int wid = xcd_swz(blockIdx.x + nx * blockIdx.y, nwg);
  const int m0 = (wid / nx) * 256, n0 = (wid % nx) * 256;

  f32x4 acc[8][4] = {};

  const int lrow = lane >> 3;
  const int scl  = (lane & 7) ^ lrow;             // swizzled logical chunk
  const u16* Ag = A  + (size_t)(m0 + w * 32 + lrow) * K + scl * 8;
  const u16* Bg = Bm + (size_t)(n0 + w * 32 + lrow) * K + scl * 8;

  const int co0 = ((qd)     ^ (ln & 7)) * 8;
  const int co1 = ((4 + qd) ^ (ln & 7)) * 8;

  auto STAGE = [&](int buf, int k0) {
#pragma unroll
    for (int r = 0; r < 4; ++r) {
      GLL(Ag + (size_t)(r * 8) * K + k0, As[buf] + (w * 4 + r) * 512);
      GLL(Bg + (size_t)(r * 8) * K + k0, Bs[buf] + (w * 4 + r) * 512);
    }
  };

  auto COMPUTE = [&](int buf) {
#pragma unroll
    for (int kk = 0; kk < 2; ++kk) {
      const int co = kk ? co1 : co0;
      bf16x8 af[8], bf[4];
#pragma unroll
      for (int t = 0; t < 8; ++t)
        af[t] = *(const bf16x8*)&As[buf][(wr * 128 + t * 16 + ln) * 64 + co];
#pragma unroll
      for (int t = 0; t < 4; ++t)
        bf[t] = *(const bf16x8*)&Bs[buf][(wc * 64 + t * 16 + ln) * 64 + co];
      __builtin_amdgcn_s_setprio(1);
#pragma unroll
      for (int i = 0; i < 8; ++i)
#pragma unroll
        for (int j = 0; j < 4; ++j)
          acc[i][j] = __builtin_amdgcn_mfma_f32_16x16x32_bf16(af[i], bf[j], acc[i][j], 0, 0, 0);
      __builtin_amdgcn_s_setprio(0);
    }
  };

  const int nk = K >> 6;
  STAGE(0, 0);                         // prologue
  for (int t = 0; t < nk; ++t) {
    const int p = t & 1;
    __syncthreads();                   // buf[p] DMA done; buf[p] readers (t-1) retired
    if (t + 1 < nk) STAGE(1 - p, (t + 1) * 64);
    COMPUTE(p);
  }

#pragma unroll
  for (int i = 0; i < 8; ++i) {
    int row = m0 + wr * 128 + i * 16 + qd * 4;
#pragma unroll
    for (int j = 0; j < 4; ++j) {
      int col = n0 + wc * 64 + j * 16 + ln;
      float bv = bias[col];
#pragma unroll
      for (int r = 0; r < 4; ++r) {
        float v = acc[i][j][r] + bv;
        if (RELU) v = fmaxf(v, 0.f);
        Cout[(size_t)(row + r) * N + col] = f2b(v);
      }
    }
  }
}

// ---------------------------------------------------------------- flash attention
// R9-proven shape: 128 q-rows/block (grid 512), 4 waves x 32 q-rows; KT=64
// ping-pong dbuf via GLL + 16B-granule XOR swizzle; ONE barrier per tile.
// UNSHIFTED softmax (logits bounded). SWAPPED QK^T (S^T = mfma(K,Q));
// P-store = 8 packed 8B writes; Ps swizzled like Ks/Vt; row sums via a
// ones-vector MFMA. XCD swizzle for K/V L2 residency.
// (R10 lesson: QBLK=64 regresses — K/V fragment reads stop amortizing.)
__global__ __launch_bounds__(256, 2) void attn_kernel(const u16* __restrict__ Q,
                                                      const u16* __restrict__ Km,
                                                      const u16* __restrict__ vT,
                                                      u16* __restrict__ O) {
  __shared__ __align__(16) u16 Ks[2][64 * 64];
  __shared__ __align__(16) u16 Vt[2][64 * 64];
  __shared__ __align__(16) u16 Ps[4][32 * 64];

  const int tid = threadIdx.x, lane = tid & 63, w = tid >> 6;
  const int ln = lane & 15, qd = lane >> 4;
  const int flat = blockIdx.x + 16 * (blockIdx.y + 16 * blockIdx.z);
  const int wid = xcd_swz(flat, 512);
  const int qi = wid & 15, head = (wid >> 4) & 15, b = wid >> 8;
  const int wq0 = b * SEQ + qi * 128 + w * 32;
  const int hcol = head * DH;

  bf16x8 qf[2][2];
#pragma unroll
  for (int ti = 0; ti < 2; ++ti)
#pragma unroll
    for (int kk = 0; kk < 2; ++kk)
      qf[ti][kk] = *(const bf16x8*)&Q[(size_t)(wq0 + ti * 16 + ln) * DIM + hcol + kk * 32 + qd * 8];

  union { u16 u[8]; bf16x8 v; } oneu;
#pragma unroll
  for (int e = 0; e < 8; ++e) oneu.u[e] = 0x3F80;
  const bf16x8 vones = oneu.v;

  f32x4 accO[2][4] = {};
  f32x4 accL[2] = {};

  const int srow = lane >> 3;
  const int scl  = (lane & 7) ^ srow;
  const u16* Kg = Km + (size_t)(b * SEQ + w * 16 + srow) * DIM + hcol + scl * 8;
  const u16* Vg = vT + (size_t)(hcol + w * 16 + srow) * MROWS + b * SEQ + scl * 8;
  u16* Pw = Ps[w];
  const int swz = ln & 7;

#pragma unroll
  for (int r = 0; r < 2; ++r) {
    GLL(Kg + (size_t)(r * 8) * DIM,   &Ks[0][(w * 2 + r) * 512]);
    GLL(Vg + (size_t)(r * 8) * MROWS, &Vt[0][(w * 2 + r) * 512]);
  }

  for (int t = 0; t < SEQ / 64; ++t) {
    const int p = t & 1;
    const int kt = t * 64;
    __syncthreads();

    if (t + 1 < SEQ / 64) {
      const int kt2 = kt + 64;
#pragma unroll
      for (int r = 0; r < 2; ++r) {
        GLL(Kg + (size_t)(kt2 + r * 8) * DIM,   &Ks[1 - p][(w * 2 + r) * 512]);
        GLL(Vg + (size_t)(r * 8) * MROWS + kt2, &Vt[1 - p][(w * 2 + r) * 512]);
      }
    }

    f32x4 sacc[4][2] = {};
#pragma unroll
    for (int kk = 0; kk < 2; ++kk) {
      bf16x8 kf[4];
#pragma unroll
      for (int tj = 0; tj < 4; ++tj)
        kf[tj] = *(const bf16x8*)&Ks[p][(tj * 16 + ln) * 64 + (((kk * 4 + qd) ^ swz) * 8)];
      __builtin_amdgcn_s_setprio(1);
#pragma unroll
      for (int tj = 0; tj < 4; ++tj)
#pragma unroll
        for (int ti = 0; ti < 2; ++ti)
          sacc[tj][ti] = __builtin_amdgcn_mfma_f32_16x16x32_bf16(kf[tj], qf[ti][kk], sacc[tj][ti], 0, 0, 0);
      __builtin_amdgcn_s_setprio(0);
    }

#pragma unroll
    for (int tj = 0; tj < 4; ++tj)
#pragma unroll
      for (int ti = 0; ti < 2; ++ti) {
        uint lo = pkbf2(__expf(sacc[tj][ti][0]), __expf(sacc[tj][ti][1]));
        uint hi = pkbf2(__expf(sacc[tj][ti][2]), __expf(sacc[tj][ti][3]));
        *(uint2*)&Pw[(ti * 16 + ln) * 64 + (((2 * tj + (qd >> 1)) ^ swz) * 8) + (qd & 1) * 4] =
            make_uint2(lo, hi);
      }

#pragma unroll
    for (int kk = 0; kk < 2; ++kk) {
      bf16x8 pf[2], vf[4];
#pragma unroll
      for (int ti = 0; ti < 2; ++ti)
        pf[ti] = *(const bf16x8*)&Pw[(ti * 16 + ln) * 64 + (((kk * 4 + qd) ^ swz) * 8)];
#pragma unroll
      for (int tjv = 0; tjv < 4; ++tjv)
        vf[tjv] = *(const bf16x8*)&Vt[p][(tjv * 16 + ln) * 64 + (((kk * 4 + qd) ^ swz) * 8)];
      __builtin_amdgcn_s_setprio(1);
#pragma unroll
      for (int ti = 0; ti < 2; ++ti) {
#pragma unroll
        for (int tjv = 0; tjv < 4; ++tjv)
          accO[ti][tjv] = __builtin_amdgcn_mfma_f32_16x16x32_bf16(pf[ti], vf[tjv], accO[ti][tjv], 0, 0, 0);
        accL[ti] = __builtin_amdgcn_mfma_f32_16x16x32_bf16(pf[ti], vones, accL[ti], 0, 0, 0);
      }
      __builtin_amdgcn_s_setprio(0);
    }
  }

#pragma unroll
  for (int ti = 0; ti < 2; ++ti)
#pragma unroll
    for (int r = 0; r < 4; ++r) {
      float inv = 1.f / accL[ti][r];
#pragma unroll
      for (int tjv = 0; tjv < 4; ++tjv)
        O[(size_t)(wq0 + ti * 16 + qd * 4 + r) * DIM + hcol + tjv * 16 + ln] =
            f2b(accO[ti][tjv][r] * inv);
    }
}

// ---------------------------------------------------------------- launch
extern "C" void kernel_launch(void* const* d_in, const int* in_sizes, int n_in,
                              void* d_out, int out_size, void* d_ws, size_t ws_size,
                              hipStream_t stream) {
  const float* x  = (const float*)d_in[0];
  const float* wq = (const float*)d_in[1];
  const float* bq = (const float*)d_in[2];
  const float* wk = (const float*)d_in[3];
  const float* bk = (const float*)d_in[4];
  const float* wv = (const float*)d_in[5];
  const float* bv = (const float*)d_in[6];
  const float* wo = (const float*)d_in[7];
  const float* bo = (const float*)d_in[8];
  const float* w1 = (const float*)d_in[9];
  const float* b1 = (const float*)d_in[10];
  const float* w2 = (const float*)d_in[11];
  const float* b2 = (const float*)d_in[12];
  float* out = (float*)d_out;
  char* ws = (char*)d_ws;

  const size_t MB = 1u << 20;
  u16*   h    = (u16*)(ws + 0);          // 8 MB (reused as y)
  u16*   q    = (u16*)(ws + 8  * MB);    // 8 MB
  u16*   k    = (u16*)(ws + 16 * MB);    // 8 MB
  u16*   v    = (u16*)(ws + 24 * MB);    // 8 MB  (vT: DIM x MROWS)
  u16*   o    = (u16*)(ws + 32 * MB);    // 8 MB
  u16*   r    = (u16*)(ws + 8  * MB);    // 32 MB, reuses q..o region (after attention done)
  float* ares = (float*)(ws + 40 * MB);  // 16 MB fp32
  u16*   wqb  = (u16*)(ws + 56 * MB);
  u16*   wkb  = (u16*)(ws + 58 * MB);
  u16*   wvb  = (u16*)(ws + 60 * MB);
  u16*   wob  = (u16*)(ws + 62 * MB);
  u16*   w1b  = (u16*)(ws + 64 * MB);    // 8 MB
  u16*   w2b  = (u16*)(ws + 72 * MB);    // 8 MB
  float* stats= (float*)(ws + 80 * MB);  // 8 floats
  u16*   y    = h;

  (void)hipMemsetAsync(stats, 0, 64, stream);

  // weights -> bf16 (2 fused launches)
  cvt4_kernel<<<dim3(512, 4),  256, 0, stream>>>(wq, wk, wv, wo, wqb, wkb, wvb, wob, DIM * DIM);
  cvt4_kernel<<<dim3(2048, 2), 256, 0, stream>>>(w1, w2, w1, w2, w1b, w2b, w1b, w2b, FFD * DIM);

  // LN1
  reduce_stats_kernel<<<dim3(64, 2), 256, 0, stream>>>(x, stats);
  ln_apply_kernel<<<4096, 256, 0, stream>>>(x, stats, h);

  // QKV: TN=64 triple-buf counted-vmcnt, 512 blocks/proj (2 blocks/CU)
  gemm_qkv_kernel<<<dim3(16, 32, 3), 256, 0, stream>>>(h, wqb, wkb, wvb, bq, bk, bv, q, k, v);

  // attention: 128-row q-tiles -> 512 blocks (R9 shape)
  attn_kernel<<<dim3(16, 16, 2), 256, 0, stream>>>(q, k, v, o);

  // out-proj + residual(x) -> ares (fp32), with FUSED LN2 stats
  gemm_bt_kernel<64, 0, 1, 0, 1, 1><<<dim3(16, 32), 256, 0, stream>>>(o, wob, bo, x, ares, stats + 4, MROWS, DIM, DIM);

  // LN2 apply (stats already accumulated by out-proj epilogue)
  ln_apply_kernel<<<4096, 256, 0, stream>>>(ares, stats + 4, y);

  // FFN-1: 256x256 8-wave kernel, grid 16x16 = 256 blocks (1/CU, 8 waves)
  gemm256_kernel<1><<<dim3(16, 16), 512, 0, stream>>>(y, w1b, b1, r, MROWS, FFD, DIM);

  // FFN-2: TN=64 triple-buf counted-vmcnt, grid 512 (2 blocks/CU)
  gemm_bt_kernel<64, 0, 1, 0, 1, 0><<<dim3(16, 32), 256, 0, stream>>>(r, w2b, b2, x, out, nullptr, MROWS, DIM, FFD);
}

// Round 12
// 398.600 us; speedup vs baseline: 1.0694x; 1.0694x over previous
//
#include <hip/hip_runtime.h>
#include <cstdint>
#include <cstddef>

typedef unsigned short u16;
typedef unsigned int uint;
typedef __bf16 bf16x8 __attribute__((ext_vector_type(8)));
typedef float f32x4 __attribute__((ext_vector_type(4)));

#define BATCH 2
#define SEQ 2048
#define DIM 1024
#define NH 16
#define DH 64
#define FFD 4096
#define MROWS 4096            // BATCH*SEQ
#define PER_BATCH 2097152     // SEQ*DIM

__device__ __forceinline__ u16 f2b(float f) {
  uint u = __builtin_bit_cast(uint, f);
  u += 0x7FFFu + ((u >> 16) & 1u);   // RNE
  return (u16)(u >> 16);
}

// pack 2 floats -> 2 bf16 in one u32; native casts are RNE (identical to f2b)
__device__ __forceinline__ uint pkbf2(float a, float b) {
  u16 x = __builtin_bit_cast(u16, (__bf16)a);
  u16 y = __builtin_bit_cast(u16, (__bf16)b);
  return (uint)x | ((uint)y << 16);
}

// XCD-aware bijective block swizzle (requires nwg % 8 == 0 — true here).
__device__ __forceinline__ int xcd_swz(int flat, int nwg) {
  return (flat & 7) * (nwg >> 3) + (flat >> 3);
}

// async global->LDS, 16B per lane; LDS dest is wave-uniform base + lane*16
#define GLL(gp, lp)                                                            \
  __builtin_amdgcn_global_load_lds(                                            \
      (const __attribute__((address_space(1))) void*)(gp),                     \
      (__attribute__((address_space(3))) void*)(lp), 16, 0, 0)

// ---------------------------------------------------------------- elementwise
__global__ __launch_bounds__(256) void cvt4_kernel(const float* __restrict__ s0,
                                                   const float* __restrict__ s1,
                                                   const float* __restrict__ s2,
                                                   const float* __restrict__ s3,
                                                   u16* d0, u16* d1, u16* d2, u16* d3,
                                                   int n) {
  int t = blockIdx.y;
  const float* src = (t == 0) ? s0 : (t == 1) ? s1 : (t == 2) ? s2 : s3;
  u16* dst = (t == 0) ? d0 : (t == 1) ? d1 : (t == 2) ? d2 : d3;
  int i = (blockIdx.x * 256 + threadIdx.x) * 8;
  if (i >= n) return;
  float4 a = *(const float4*)(src + i);
  float4 b = *(const float4*)(src + i + 4);
  uint4 o;
  o.x = f2b(a.x) | ((uint)f2b(a.y) << 16);
  o.y = f2b(a.z) | ((uint)f2b(a.w) << 16);
  o.z = f2b(b.x) | ((uint)f2b(b.y) << 16);
  o.w = f2b(b.z) | ((uint)f2b(b.w) << 16);
  *(uint4*)(dst + i) = o;
}

__global__ __launch_bounds__(256) void reduce_stats_kernel(const float* __restrict__ x,
                                                           float* __restrict__ stats) {
  int b = blockIdx.y;
  const float* p = x + (size_t)b * PER_BATCH;
  float s = 0.f, ss = 0.f;
  int stride = gridDim.x * 256 * 4;
  for (int i = (blockIdx.x * 256 + threadIdx.x) * 4; i < PER_BATCH; i += stride) {
    float4 v = *(const float4*)(p + i);
    s  += (v.x + v.y) + (v.z + v.w);
    ss += (v.x * v.x + v.y * v.y) + (v.z * v.z + v.w * v.w);
  }
#pragma unroll
  for (int m = 32; m; m >>= 1) { s += __shfl_xor(s, m); ss += __shfl_xor(ss, m); }
  __shared__ float red[16];
  int w = threadIdx.x >> 6;
  if ((threadIdx.x & 63) == 0) { red[w] = s; red[8 + w] = ss; }
  __syncthreads();
  if (threadIdx.x == 0) {
    atomicAdd(&stats[b * 2],     red[0] + red[1] + red[2] + red[3]);
    atomicAdd(&stats[b * 2 + 1], red[8] + red[9] + red[10] + red[11]);
  }
}

__global__ __launch_bounds__(256) void ln_apply_kernel(const float* __restrict__ xin,
                                                       const float* __restrict__ stats,
                                                       u16* __restrict__ out) {
  int i = (blockIdx.x * 256 + threadIdx.x) * 4;
  int b = i >> 21;   // i / PER_BATCH
  const float inv = 1.f / (float)PER_BATCH;
  float mu = stats[b * 2] * inv;
  float var = stats[b * 2 + 1] * inv - mu * mu;
  float rs = rsqrtf(var + 1e-5f);
  float4 v = *(const float4*)(xin + i);
  uint r0 = f2b((v.x - mu) * rs) | ((uint)f2b((v.y - mu) * rs) << 16);
  uint r1 = f2b((v.z - mu) * rs) | ((uint)f2b((v.w - mu) * rs) << 16);
  *(uint2*)(out + i) = make_uint2(r0, r1);
}

// ---------------------------------------------------------------- GEMM (C = A * B^T)
// m97 structure + 16B-granule XOR swizzle on LDS tiles:
//   phys chunk = c_log ^ (row & 7); GLL source chunk scl = (lane&7)^(lane>>3)
//   keeps the DMA lane-linear. Frag-read chunk offset ((kk*4+qd)^(ln&7)) is
//   loop-invariant.
// STRUCTURE LESSONS (R3-R11):
//   - 2-phase 4-wave blocks plateau at MfmaUtil ~22%; TN=64 triple-buf
//     counted vmcnt(6) recovers ~5% (R9). 8-wave 256^2 exits the plateau
//     (R6 FFN-1 ~1.7x) but needs a full grid (R8: 192 blocks neutral).
//   - ATOMIC split-K epilogue NOT viable (R7: 64MB RMW serializes at L2).
//   - attn: QBLK=64 for occupancy REGRESSED (R10) — overhead-bound.
//   - __shared__ is PER TEMPLATE INSTANTIATION: two gemm_bt_body call sites
//     in one kernel SUM their LDS (R11: QKV 144KB -> 1 block/CU, 92us).
//     trv is therefore a RUNTIME arg (wave-uniform epilogue branch, proven
//     correct in R8's gemm256_qkv) so multi-variant kernels keep ONE body.
// STATS: fuse LayerNorm sum/sumsq into the fp32 epilogue (wave-shuffle
//   reduce + 2 atomicAdds/wave; blocks never straddle the batch boundary).
template <int TN, int RELU, int RESID, int OUTBF, int DBUF, int STATS>
__device__ __forceinline__ void gemm_bt_body(const u16* __restrict__ A,
                                             const u16* __restrict__ Bm,
                                             const float* __restrict__ bias,
                                             const float* __restrict__ resid,
                                             void* __restrict__ Cout,
                                             float* __restrict__ stats,
                                             int M, int N, int K,
                                             int m0, int n0, float oscale, int trv) {
  constexpr int AI  = (TN == 128) ? 4 : 2;   // 16-row acc tiles per wave
  constexpr int BCH = (TN == 128) ? 4 : 2;   // B staging chunks per wave
  constexpr int NB  = DBUF ? 3 : 1;          // LDS buffers (3 = counted pipeline)
  __shared__ __align__(16) u16 As[NB][128 * 64];
  __shared__ __align__(16) u16 Bs[NB][TN * 64];
  const int tid = threadIdx.x;
  const int lane = tid & 63, w = tid >> 6;
  const int wr = (TN == 128) ? (w >> 1) : w;
  const int wc = (TN == 128) ? (w & 1) : 0;
  const int ln = lane & 15, qd = lane >> 4;

  f32x4 acc[AI][4] = {};

  const int lrow = lane >> 3;
  const int scl  = (lane & 7) ^ lrow;        // swizzled logical chunk
  const u16* Ag = A  + (size_t)(m0 + w * 32 + lrow) * K + scl * 8;
  const u16* Bg = Bm + (size_t)(n0 + w * 8 * BCH + lrow) * K + scl * 8;

  const int co0 = ((qd)     ^ (ln & 7)) * 8;
  const int co1 = ((4 + qd) ^ (ln & 7)) * 8;

  auto STAGE = [&](int buf, int k0) {
#pragma unroll
    for (int r = 0; r < 4; ++r)
      GLL(Ag + (size_t)(r * 8) * K + k0, As[buf] + (w * 4 + r) * 512);
#pragma unroll
    for (int r = 0; r < BCH; ++r)
      GLL(Bg + (size_t)(r * 8) * K + k0, Bs[buf] + (w * BCH + r) * 512);
  };

  auto COMPUTE = [&](int buf) {
#pragma unroll
    for (int kk = 0; kk < 2; ++kk) {
      const int co = kk ? co1 : co0;
      bf16x8 af[AI], bf[4];
#pragma unroll
      for (int t = 0; t < AI; ++t)
        af[t] = *(const bf16x8*)&As[buf][(wr * (AI * 16) + t * 16 + ln) * 64 + co];
#pragma unroll
      for (int t = 0; t < 4; ++t)
        bf[t] = *(const bf16x8*)&Bs[buf][(wc * 64 + t * 16 + ln) * 64 + co];
#pragma unroll
      for (int i = 0; i < AI; ++i)
#pragma unroll
        for (int j = 0; j < 4; ++j)
          acc[i][j] = __builtin_amdgcn_mfma_f32_16x16x32_bf16(af[i], bf[j], acc[i][j], 0, 0, 0);
    }
  };

  if constexpr (NB == 3) {
    // depth-2 counted pipeline: 6 GLLs per wave per STAGE (T4: never drain
    // vmcnt to 0 in the loop). Hazard: buffer (t+2)%3 was last read in
    // COMPUTE(t-1) whose ds_reads retire before any wave passes barrier t.
    const int nk = K >> 6;
    STAGE(0, 0);
    STAGE(1, 64);
    int c = 0, s = 2;
    int t = 0;
    for (; t + 1 < nk; ++t) {
      asm volatile("s_waitcnt vmcnt(6)" ::: "memory");
      __builtin_amdgcn_s_barrier();
      __builtin_amdgcn_sched_barrier(0);
      if (t + 2 < nk) STAGE(s, (t + 2) * 64);
      COMPUTE(c);
      c = (c == 2) ? 0 : c + 1;
      s = (s == 2) ? 0 : s + 1;
    }
    asm volatile("s_waitcnt vmcnt(0)" ::: "memory");
    __builtin_amdgcn_s_barrier();
    __builtin_amdgcn_sched_barrier(0);
    COMPUTE(c);
  } else {
    for (int k0 = 0; k0 < K; k0 += 64) {
      __syncthreads();
      STAGE(0, k0);
      __syncthreads();
      COMPUTE(0);
    }
  }

  float sum = 0.f, ssum = 0.f;   // LN stats (STATS path)

#pragma unroll
  for (int i = 0; i < AI; ++i) {
    int row = m0 + wr * (AI * 16) + i * 16 + qd * 4;
#pragma unroll
    for (int j = 0; j < 4; ++j) {
      int col = n0 + wc * 64 + j * 16 + ln;
      float bv = bias[col];
      if (trv) {
        // transposed bf16 store: vT[col][row..row+3] as one 8B write
        union { uint2 u2; u16 us[4]; } pk;
#pragma unroll
        for (int r = 0; r < 4; ++r) pk.us[r] = f2b(acc[i][j][r] + bv);
        *(uint2*)&((u16*)Cout)[(size_t)col * MROWS + row] = pk.u2;
      } else {
#pragma unroll
        for (int r = 0; r < 4; ++r) {
          float v = (acc[i][j][r] + bv) * oscale;
          if (RELU) v = fmaxf(v, 0.f);
          size_t off = (size_t)(row + r) * N + col;
          if (RESID) v += resid[off];
          if (OUTBF) ((u16*)Cout)[off] = f2b(v);
          else       ((float*)Cout)[off] = v;
          if (STATS) { sum += v; ssum += v * v; }
        }
      }
    }
  }

  if (STATS) {
    // all of this block's rows are in one batch (128 | 2048)
#pragma unroll
    for (int m = 32; m; m >>= 1) { sum += __shfl_xor(sum, m); ssum += __shfl_xor(ssum, m); }
    if (lane == 0) {
      int b = m0 >> 11;   // row / SEQ
      atomicAdd(&stats[b * 2], sum);
      atomicAdd(&stats[b * 2 + 1], ssum);
    }
  }
}

template <int TN, int RELU, int RESID, int OUTBF, int DBUF, int STATS>
__global__ __launch_bounds__(256) void gemm_bt_kernel(const u16* __restrict__ A,
                                                      const u16* __restrict__ Bm,
                                                      const float* __restrict__ bias,
                                                      const float* __restrict__ resid,
                                                      void* __restrict__ Cout,
                                                      float* __restrict__ stats,
                                                      int M, int N, int K) {
  const int nx = gridDim.x;
  const int nwg = nx * gridDim.y;
  const int wid = xcd_swz(blockIdx.x + nx * blockIdx.y, nwg);
  gemm_bt_body<TN, RELU, RESID, OUTBF, DBUF, STATS>(A, Bm, bias, resid, Cout, stats,
                                                    M, N, K,
                                                    (wid / nx) * 128, (wid % nx) * TN,
                                                    1.0f, 0);
}

// fused QKV on the R9-proven TN=64 triple-buf structure: per proj 512 blocks
// (16 N-tiles x 32 M-tiles), z selects projection; ONE gemm_bt_body call
// site (runtime trv/oscale) -> 72 KB LDS -> 2 blocks/CU (R11 lesson!).
// V (z==2) writes transposed vT; Q (z==0) pre-scaled by 0.25 (ref's bug).
__global__ __launch_bounds__(256) void gemm_qkv_kernel(const u16* __restrict__ A,
                                                       const u16* B0, const u16* B1, const u16* B2,
                                                       const float* c0, const float* c1, const float* c2,
                                                       u16* o0, u16* o1, u16* o2) {
  int z = blockIdx.z;
  const int wid = xcd_swz(blockIdx.x + 16 * blockIdx.y, 512);
  const int m0 = (wid >> 4) * 128, n0 = (wid & 15) * 64;
  const u16* Bm = (z == 0) ? B0 : (z == 1) ? B1 : B2;
  const float* bias = (z == 0) ? c0 : (z == 1) ? c1 : c2;
  u16* Cout = (z == 0) ? o0 : (z == 1) ? o1 : o2;
  const float sc = (z == 0) ? 0.25f : 1.0f;
  gemm_bt_body<64, 0, 0, 1, 1, 0>(A, Bm, bias, nullptr, Cout, nullptr,
                                  MROWS, DIM, DIM, m0, n0, sc, z == 2);
}

// ---------------------------------------------------------------- 256x256 GEMM
// 8-wave (512-thread) 256x256 tile, BK=64, wave tile 128x64 (2M x 4N).
// Exits the 4-wave 2-phase plateau (R6: FFN-1 ~1.7x). Single-barrier
// ping-pong dbuf (128 KB LDS, 1 block/CU of 8 waves) — depth-1 suffices:
// COMPUTE (~2000cy) >> GLL latency.
template <int RELU>
__global__ __launch_bounds__(512, 2) void gemm256_kernel(const u16* __restrict__ A,
                                                         const u16* __restrict__ Bm,
                                                         const float* __restrict__ bias,
                                                         u16* __restrict__ Cout,
                                                         int M, int N, int K) {
  __shared__ __align__(16) u16 As[2][256 * 64];   // 32 KB x2
  __shared__ __align__(16) u16 Bs[2][256 * 64];   // 32 KB x2  (total 128 KB)
  const int tid = threadIdx.x;
  const int lane = tid & 63, w = tid >> 6;        // 8 waves
  const int wr = w >> 2, wc = w & 3;              // 2M x 4N
  const int ln = lane & 15, qd = lane >> 4;

  const int nx = gridDim.x;
  const int nwg = nx * gridDim.y;
  const int wid = xcd_swz(blockIdx.x + nx * blockIdx.y, nwg);
  const int m0 = (wid / nx) * 256, n0 = (wid % nx) * 256;

  f32x4 acc[8][4] = {};

  const int lrow = lane >> 3;
  const int scl  = (lane & 7) ^ lrow;             // swizzled logical chunk
  const u16* Ag = A  + (size_t)(m0 + w * 32 + lrow) * K + scl * 8;
  const u16* Bg = Bm + (size_t)(n0 + w * 32 + lrow) * K + scl * 8;

  const int co0 = ((qd)     ^ (ln & 7)) * 8;
  const int co1 = ((4 + qd) ^ (ln & 7)) * 8;

  auto STAGE = [&](int buf, int k0) {
#pragma unroll
    for (int r = 0; r < 4; ++r) {
      GLL(Ag + (size_t)(r * 8) * K + k0, As[buf] + (w * 4 + r) * 512);
      GLL(Bg + (size_t)(r * 8) * K + k0, Bs[buf] + (w * 4 + r) * 512);
    }
  };

  auto COMPUTE = [&](int buf) {
#pragma unroll
    for (int kk = 0; kk < 2; ++kk) {
      const int co = kk ? co1 : co0;
      bf16x8 af[8], bf[4];
#pragma unroll
      for (int t = 0; t < 8; ++t)
        af[t] = *(const bf16x8*)&As[buf][(wr * 128 + t * 16 + ln) * 64 + co];
#pragma unroll
      for (int t = 0; t < 4; ++t)
        bf[t] = *(const bf16x8*)&Bs[buf][(wc * 64 + t * 16 + ln) * 64 + co];
      __builtin_amdgcn_s_setprio(1);
#pragma unroll
      for (int i = 0; i < 8; ++i)
#pragma unroll
        for (int j = 0; j < 4; ++j)
          acc[i][j] = __builtin_amdgcn_mfma_f32_16x16x32_bf16(af[i], bf[j], acc[i][j], 0, 0, 0);
      __builtin_amdgcn_s_setprio(0);
    }
  };

  const int nk = K >> 6;
  STAGE(0, 0);                         // prologue
  for (int t = 0; t < nk; ++t) {
    const int p = t & 1;
    __syncthreads();                   // buf[p] DMA done; buf[p] readers (t-1) retired
    if (t + 1 < nk) STAGE(1 - p, (t + 1) * 64);
    COMPUTE(p);
  }

#pragma unroll
  for (int i = 0; i < 8; ++i) {
    int row = m0 + wr * 128 + i * 16 + qd * 4;
#pragma unroll
    for (int j = 0; j < 4; ++j) {
      int col = n0 + wc * 64 + j * 16 + ln;
      float bv = bias[col];
#pragma unroll
      for (int r = 0; r < 4; ++r) {
        float v = acc[i][j][r] + bv;
        if (RELU) v = fmaxf(v, 0.f);
        Cout[(size_t)(row + r) * N + col] = f2b(v);
      }
    }
  }
}

// ---------------------------------------------------------------- flash attention
// R9-proven shape: 128 q-rows/block (grid 512), 4 waves x 32 q-rows; KT=64
// ping-pong dbuf via GLL + 16B-granule XOR swizzle; ONE barrier per tile.
// UNSHIFTED softmax (logits bounded). SWAPPED QK^T (S^T = mfma(K,Q));
// P-store = 8 packed 8B writes; Ps swizzled like Ks/Vt; row sums via a
// ones-vector MFMA. XCD swizzle for K/V L2 residency.
// (R10 lesson: QBLK=64 regresses — K/V fragment reads stop amortizing.)
__global__ __launch_bounds__(256, 2) void attn_kernel(const u16* __restrict__ Q,
                                                      const u16* __restrict__ Km,
                                                      const u16* __restrict__ vT,
                                                      u16* __restrict__ O) {
  __shared__ __align__(16) u16 Ks[2][64 * 64];
  __shared__ __align__(16) u16 Vt[2][64 * 64];
  __shared__ __align__(16) u16 Ps[4][32 * 64];

  const int tid = threadIdx.x, lane = tid & 63, w = tid >> 6;
  const int ln = lane & 15, qd = lane >> 4;
  const int flat = blockIdx.x + 16 * (blockIdx.y + 16 * blockIdx.z);
  const int wid = xcd_swz(flat, 512);
  const int qi = wid & 15, head = (wid >> 4) & 15, b = wid >> 8;
  const int wq0 = b * SEQ + qi * 128 + w * 32;
  const int hcol = head * DH;

  bf16x8 qf[2][2];
#pragma unroll
  for (int ti = 0; ti < 2; ++ti)
#pragma unroll
    for (int kk = 0; kk < 2; ++kk)
      qf[ti][kk] = *(const bf16x8*)&Q[(size_t)(wq0 + ti * 16 + ln) * DIM + hcol + kk * 32 + qd * 8];

  union { u16 u[8]; bf16x8 v; } oneu;
#pragma unroll
  for (int e = 0; e < 8; ++e) oneu.u[e] = 0x3F80;
  const bf16x8 vones = oneu.v;

  f32x4 accO[2][4] = {};
  f32x4 accL[2] = {};

  const int srow = lane >> 3;
  const int scl  = (lane & 7) ^ srow;
  const u16* Kg = Km + (size_t)(b * SEQ + w * 16 + srow) * DIM + hcol + scl * 8;
  const u16* Vg = vT + (size_t)(hcol + w * 16 + srow) * MROWS + b * SEQ + scl * 8;
  u16* Pw = Ps[w];
  const int swz = ln & 7;

#pragma unroll
  for (int r = 0; r < 2; ++r) {
    GLL(Kg + (size_t)(r * 8) * DIM,   &Ks[0][(w * 2 + r) * 512]);
    GLL(Vg + (size_t)(r * 8) * MROWS, &Vt[0][(w * 2 + r) * 512]);
  }

  for (int t = 0; t < SEQ / 64; ++t) {
    const int p = t & 1;
    const int kt = t * 64;
    __syncthreads();

    if (t + 1 < SEQ / 64) {
      const int kt2 = kt + 64;
#pragma unroll
      for (int r = 0; r < 2; ++r) {
        GLL(Kg + (size_t)(kt2 + r * 8) * DIM,   &Ks[1 - p][(w * 2 + r) * 512]);
        GLL(Vg + (size_t)(r * 8) * MROWS + kt2, &Vt[1 - p][(w * 2 + r) * 512]);
      }
    }

    f32x4 sacc[4][2] = {};
#pragma unroll
    for (int kk = 0; kk < 2; ++kk) {
      bf16x8 kf[4];
#pragma unroll
      for (int tj = 0; tj < 4; ++tj)
        kf[tj] = *(const bf16x8*)&Ks[p][(tj * 16 + ln) * 64 + (((kk * 4 + qd) ^ swz) * 8)];
      __builtin_amdgcn_s_setprio(1);
#pragma unroll
      for (int tj = 0; tj < 4; ++tj)
#pragma unroll
        for (int ti = 0; ti < 2; ++ti)
          sacc[tj][ti] = __builtin_amdgcn_mfma_f32_16x16x32_bf16(kf[tj], qf[ti][kk], sacc[tj][ti], 0, 0, 0);
      __builtin_amdgcn_s_setprio(0);
    }

#pragma unroll
    for (int tj = 0; tj < 4; ++tj)
#pragma unroll
      for (int ti = 0; ti < 2; ++ti) {
        uint lo = pkbf2(__expf(sacc[tj][ti][0]), __expf(sacc[tj][ti][1]));
        uint hi = pkbf2(__expf(sacc[tj][ti][2]), __expf(sacc[tj][ti][3]));
        *(uint2*)&Pw[(ti * 16 + ln) * 64 + (((2 * tj + (qd >> 1)) ^ swz) * 8) + (qd & 1) * 4] =
            make_uint2(lo, hi);
      }

#pragma unroll
    for (int kk = 0; kk < 2; ++kk) {
      bf16x8 pf[2], vf[4];
#pragma unroll
      for (int ti = 0; ti < 2; ++ti)
        pf[ti] = *(const bf16x8*)&Pw[(ti * 16 + ln) * 64 + (((kk * 4 + qd) ^ swz) * 8)];
#pragma unroll
      for (int tjv = 0; tjv < 4; ++tjv)
        vf[tjv] = *(const bf16x8*)&Vt[p][(tjv * 16 + ln) * 64 + (((kk * 4 + qd) ^ swz) * 8)];
      __builtin_amdgcn_s_setprio(1);
#pragma unroll
      for (int ti = 0; ti < 2; ++ti) {
#pragma unroll
        for (int tjv = 0; tjv < 4; ++tjv)
          accO[ti][tjv] = __builtin_amdgcn_mfma_f32_16x16x32_bf16(pf[ti], vf[tjv], accO[ti][tjv], 0, 0, 0);
        accL[ti] = __builtin_amdgcn_mfma_f32_16x16x32_bf16(pf[ti], vones, accL[ti], 0, 0, 0);
      }
      __builtin_amdgcn_s_setprio(0);
    }
  }

#pragma unroll
  for (int ti = 0; ti < 2; ++ti)
#pragma unroll
    for (int r = 0; r < 4; ++r) {
      float inv = 1.f / accL[ti][r];
#pragma unroll
      for (int tjv = 0; tjv < 4; ++tjv)
        O[(size_t)(wq0 + ti * 16 + qd * 4 + r) * DIM + hcol + tjv * 16 + ln] =
            f2b(accO[ti][tjv][r] * inv);
    }
}

// ---------------------------------------------------------------- launch
extern "C" void kernel_launch(void* const* d_in, const int* in_sizes, int n_in,
                              void* d_out, int out_size, void* d_ws, size_t ws_size,
                              hipStream_t stream) {
  const float* x  = (const float*)d_in[0];
  const float* wq = (const float*)d_in[1];
  const float* bq = (const float*)d_in[2];
  const float* wk = (const float*)d_in[3];
  const float* bk = (const float*)d_in[4];
  const float* wv = (const float*)d_in[5];
  const float* bv = (const float*)d_in[6];
  const float* wo = (const float*)d_in[7];
  const float* bo = (const float*)d_in[8];
  const float* w1 = (const float*)d_in[9];
  const float* b1 = (const float*)d_in[10];
  const float* w2 = (const float*)d_in[11];
  const float* b2 = (const float*)d_in[12];
  float* out = (float*)d_out;
  char* ws = (char*)d_ws;

  const size_t MB = 1u << 20;
  u16*   h    = (u16*)(ws + 0);          // 8 MB (reused as y)
  u16*   q    = (u16*)(ws + 8  * MB);    // 8 MB
  u16*   k    = (u16*)(ws + 16 * MB);    // 8 MB
  u16*   v    = (u16*)(ws + 24 * MB);    // 8 MB  (vT: DIM x MROWS)
  u16*   o    = (u16*)(ws + 32 * MB);    // 8 MB
  u16*   r    = (u16*)(ws + 8  * MB);    // 32 MB, reuses q..o region (after attention done)
  float* ares = (float*)(ws + 40 * MB);  // 16 MB fp32
  u16*   wqb  = (u16*)(ws + 56 * MB);
  u16*   wkb  = (u16*)(ws + 58 * MB);
  u16*   wvb  = (u16*)(ws + 60 * MB);
  u16*   wob  = (u16*)(ws + 62 * MB);
  u16*   w1b  = (u16*)(ws + 64 * MB);    // 8 MB
  u16*   w2b  = (u16*)(ws + 72 * MB);    // 8 MB
  float* stats= (float*)(ws + 80 * MB);  // 8 floats
  u16*   y    = h;

  (void)hipMemsetAsync(stats, 0, 64, stream);

  // weights -> bf16 (2 fused launches)
  cvt4_kernel<<<dim3(512, 4),  256, 0, stream>>>(wq, wk, wv, wo, wqb, wkb, wvb, wob, DIM * DIM);
  cvt4_kernel<<<dim3(2048, 2), 256, 0, stream>>>(w1, w2, w1, w2, w1b, w2b, w1b, w2b, FFD * DIM);

  // LN1
  reduce_stats_kernel<<<dim3(64, 2), 256, 0, stream>>>(x, stats);
  ln_apply_kernel<<<4096, 256, 0, stream>>>(x, stats, h);

  // QKV: TN=64 triple-buf counted-vmcnt, 512 blocks/proj (2 blocks/CU)
  gemm_qkv_kernel<<<dim3(16, 32, 3), 256, 0, stream>>>(h, wqb, wkb, wvb, bq, bk, bv, q, k, v);

  // attention: 128-row q-tiles -> 512 blocks (R9 shape)
  attn_kernel<<<dim3(16, 16, 2), 256, 0, stream>>>(q, k, v, o);

  // out-proj + residual(x) -> ares (fp32), with FUSED LN2 stats
  gemm_bt_kernel<64, 0, 1, 0, 1, 1><<<dim3(16, 32), 256, 0, stream>>>(o, wob, bo, x, ares, stats + 4, MROWS, DIM, DIM);

  // LN2 apply (stats already accumulated by out-proj epilogue)
  ln_apply_kernel<<<4096, 256, 0, stream>>>(ares, stats + 4, y);

  // FFN-1: 256x256 8-wave kernel, grid 16x16 = 256 blocks (1/CU, 8 waves)
  gemm256_kernel<1><<<dim3(16, 16), 512, 0, stream>>>(y, w1b, b1, r, MROWS, FFD, DIM);

  // FFN-2: TN=64 triple-buf counted-vmcnt, grid 512 (2 blocks/CU)
  gemm_bt_kernel<64, 0, 1, 0, 1, 0><<<dim3(16, 32), 256, 0, stream>>>(r, w2b, b2, x, out, nullptr, MROWS, DIM, FFD);
}

// Round 13
// 357.122 us; speedup vs baseline: 1.1936x; 1.1161x over previous
//
#include <hip/hip_runtime.h>
#include <cstdint>
#include <cstddef>

typedef unsigned short u16;
typedef unsigned int uint;
typedef __bf16 bf16x8 __attribute__((ext_vector_type(8)));
typedef float f32x4 __attribute__((ext_vector_type(4)));

#define BATCH 2
#define SEQ 2048
#define DIM 1024
#define NH 16
#define DH 64
#define FFD 4096
#define MROWS 4096            // BATCH*SEQ
#define PER_BATCH 2097152     // SEQ*DIM

__device__ __forceinline__ u16 f2b(float f) {
  uint u = __builtin_bit_cast(uint, f);
  u += 0x7FFFu + ((u >> 16) & 1u);   // RNE
  return (u16)(u >> 16);
}

// pack 2 floats -> 2 bf16 in one u32; native casts are RNE (identical to f2b)
__device__ __forceinline__ uint pkbf2(float a, float b) {
  u16 x = __builtin_bit_cast(u16, (__bf16)a);
  u16 y = __builtin_bit_cast(u16, (__bf16)b);
  return (uint)x | ((uint)y << 16);
}

// XCD-aware bijective block swizzle (requires nwg % 8 == 0 — true here).
__device__ __forceinline__ int xcd_swz(int flat, int nwg) {
  return (flat & 7) * (nwg >> 3) + (flat >> 3);
}

// async global->LDS, 16B per lane; LDS dest is wave-uniform base + lane*16
#define GLL(gp, lp)                                                            \
  __builtin_amdgcn_global_load_lds(                                            \
      (const __attribute__((address_space(1))) void*)(gp),                     \
      (__attribute__((address_space(3))) void*)(lp), 16, 0, 0)

// ---------------------------------------------------------------- elementwise
__global__ __launch_bounds__(256) void cvt4_kernel(const float* __restrict__ s0,
                                                   const float* __restrict__ s1,
                                                   const float* __restrict__ s2,
                                                   const float* __restrict__ s3,
                                                   u16* d0, u16* d1, u16* d2, u16* d3,
                                                   int n) {
  int t = blockIdx.y;
  const float* src = (t == 0) ? s0 : (t == 1) ? s1 : (t == 2) ? s2 : s3;
  u16* dst = (t == 0) ? d0 : (t == 1) ? d1 : (t == 2) ? d2 : d3;
  int i = (blockIdx.x * 256 + threadIdx.x) * 8;
  if (i >= n) return;
  float4 a = *(const float4*)(src + i);
  float4 b = *(const float4*)(src + i + 4);
  uint4 o;
  o.x = f2b(a.x) | ((uint)f2b(a.y) << 16);
  o.y = f2b(a.z) | ((uint)f2b(a.w) << 16);
  o.z = f2b(b.x) | ((uint)f2b(b.y) << 16);
  o.w = f2b(b.z) | ((uint)f2b(b.w) << 16);
  *(uint4*)(dst + i) = o;
}

__global__ __launch_bounds__(256) void reduce_stats_kernel(const float* __restrict__ x,
                                                           float* __restrict__ stats) {
  int b = blockIdx.y;
  const float* p = x + (size_t)b * PER_BATCH;
  float s = 0.f, ss = 0.f;
  int stride = gridDim.x * 256 * 4;
  for (int i = (blockIdx.x * 256 + threadIdx.x) * 4; i < PER_BATCH; i += stride) {
    float4 v = *(const float4*)(p + i);
    s  += (v.x + v.y) + (v.z + v.w);
    ss += (v.x * v.x + v.y * v.y) + (v.z * v.z + v.w * v.w);
  }
#pragma unroll
  for (int m = 32; m; m >>= 1) { s += __shfl_xor(s, m); ss += __shfl_xor(ss, m); }
  __shared__ float red[16];
  int w = threadIdx.x >> 6;
  if ((threadIdx.x & 63) == 0) { red[w] = s; red[8 + w] = ss; }
  __syncthreads();
  if (threadIdx.x == 0) {
    atomicAdd(&stats[b * 2],     red[0] + red[1] + red[2] + red[3]);
    atomicAdd(&stats[b * 2 + 1], red[8] + red[9] + red[10] + red[11]);
  }
}

__global__ __launch_bounds__(256) void ln_apply_kernel(const float* __restrict__ xin,
                                                       const float* __restrict__ stats,
                                                       u16* __restrict__ out) {
  int i = (blockIdx.x * 256 + threadIdx.x) * 4;
  int b = i >> 21;   // i / PER_BATCH
  const float inv = 1.f / (float)PER_BATCH;
  float mu = stats[b * 2] * inv;
  float var = stats[b * 2 + 1] * inv - mu * mu;
  float rs = rsqrtf(var + 1e-5f);
  float4 v = *(const float4*)(xin + i);
  uint r0 = f2b((v.x - mu) * rs) | ((uint)f2b((v.y - mu) * rs) << 16);
  uint r1 = f2b((v.z - mu) * rs) | ((uint)f2b((v.w - mu) * rs) << 16);
  *(uint2*)(out + i) = make_uint2(r0, r1);
}

// ---------------------------------------------------------------- GEMM (C = A * B^T)
// m97 structure + 16B-granule XOR swizzle on LDS tiles:
//   phys chunk = c_log ^ (row & 7); GLL source chunk scl = (lane&7)^(lane>>3)
//   keeps the DMA lane-linear. Frag-read chunk offset ((kk*4+qd)^(ln&7)) is
//   loop-invariant.
// STRUCTURE LESSONS (R3-R12):
//   - 2-phase 4-wave blocks plateau at MfmaUtil ~22%; TN=64 triple-buf
//     counted vmcnt(6) recovers ~5% (R9). 8-wave 256^2 exits the plateau
//     (R6 FFN-1 ~1.7x) but needs a full grid (R8: 192 blocks neutral).
//   - ATOMIC split-K epilogue NOT viable (R7: 64MB RMW serializes at L2).
//   - attn: QBLK=64 for occupancy REGRESSED (R10) — overhead-bound.
//   - __shared__ is PER TEMPLATE INSTANTIATION: two gemm_bt_body call sites
//     in one kernel SUM their LDS (R11: QKV 144KB -> 1 block/CU, 92us).
//     trv is a RUNTIME arg so multi-variant kernels keep ONE body.
//   - PER-WAVE atomics to one cache line are catastrophic (R12: fused LN
//     stats = 4096 atomicAdds to one 16B line -> +50us, MfmaUtil 4%).
//     Keep LN stats as a separate streaming reduce pass.
template <int TN, int RELU, int RESID, int OUTBF, int DBUF>
__device__ __forceinline__ void gemm_bt_body(const u16* __restrict__ A,
                                             const u16* __restrict__ Bm,
                                             const float* __restrict__ bias,
                                             const float* __restrict__ resid,
                                             void* __restrict__ Cout,
                                             int M, int N, int K,
                                             int m0, int n0, float oscale, int trv) {
  constexpr int AI  = (TN == 128) ? 4 : 2;   // 16-row acc tiles per wave
  constexpr int BCH = (TN == 128) ? 4 : 2;   // B staging chunks per wave
  constexpr int NB  = DBUF ? 3 : 1;          // LDS buffers (3 = counted pipeline)
  __shared__ __align__(16) u16 As[NB][128 * 64];
  __shared__ __align__(16) u16 Bs[NB][TN * 64];
  const int tid = threadIdx.x;
  const int lane = tid & 63, w = tid >> 6;
  const int wr = (TN == 128) ? (w >> 1) : w;
  const int wc = (TN == 128) ? (w & 1) : 0;
  const int ln = lane & 15, qd = lane >> 4;

  f32x4 acc[AI][4] = {};

  const int lrow = lane >> 3;
  const int scl  = (lane & 7) ^ lrow;        // swizzled logical chunk
  const u16* Ag = A  + (size_t)(m0 + w * 32 + lrow) * K + scl * 8;
  const u16* Bg = Bm + (size_t)(n0 + w * 8 * BCH + lrow) * K + scl * 8;

  const int co0 = ((qd)     ^ (ln & 7)) * 8;
  const int co1 = ((4 + qd) ^ (ln & 7)) * 8;

  auto STAGE = [&](int buf, int k0) {
#pragma unroll
    for (int r = 0; r < 4; ++r)
      GLL(Ag + (size_t)(r * 8) * K + k0, As[buf] + (w * 4 + r) * 512);
#pragma unroll
    for (int r = 0; r < BCH; ++r)
      GLL(Bg + (size_t)(r * 8) * K + k0, Bs[buf] + (w * BCH + r) * 512);
  };

  auto COMPUTE = [&](int buf) {
#pragma unroll
    for (int kk = 0; kk < 2; ++kk) {
      const int co = kk ? co1 : co0;
      bf16x8 af[AI], bf[4];
#pragma unroll
      for (int t = 0; t < AI; ++t)
        af[t] = *(const bf16x8*)&As[buf][(wr * (AI * 16) + t * 16 + ln) * 64 + co];
#pragma unroll
      for (int t = 0; t < 4; ++t)
        bf[t] = *(const bf16x8*)&Bs[buf][(wc * 64 + t * 16 + ln) * 64 + co];
#pragma unroll
      for (int i = 0; i < AI; ++i)
#pragma unroll
        for (int j = 0; j < 4; ++j)
          acc[i][j] = __builtin_amdgcn_mfma_f32_16x16x32_bf16(af[i], bf[j], acc[i][j], 0, 0, 0);
    }
  };

  if constexpr (NB == 3) {
    // depth-2 counted pipeline: 6 GLLs per wave per STAGE (T4: never drain
    // vmcnt to 0 in the loop). Hazard: buffer (t+2)%3 was last read in
    // COMPUTE(t-1) whose ds_reads retire before any wave passes barrier t.
    const int nk = K >> 6;
    STAGE(0, 0);
    STAGE(1, 64);
    int c = 0, s = 2;
    int t = 0;
    for (; t + 1 < nk; ++t) {
      asm volatile("s_waitcnt vmcnt(6)" ::: "memory");
      __builtin_amdgcn_s_barrier();
      __builtin_amdgcn_sched_barrier(0);
      if (t + 2 < nk) STAGE(s, (t + 2) * 64);
      COMPUTE(c);
      c = (c == 2) ? 0 : c + 1;
      s = (s == 2) ? 0 : s + 1;
    }
    asm volatile("s_waitcnt vmcnt(0)" ::: "memory");
    __builtin_amdgcn_s_barrier();
    __builtin_amdgcn_sched_barrier(0);
    COMPUTE(c);
  } else {
    for (int k0 = 0; k0 < K; k0 += 64) {
      __syncthreads();
      STAGE(0, k0);
      __syncthreads();
      COMPUTE(0);
    }
  }

#pragma unroll
  for (int i = 0; i < AI; ++i) {
    int row = m0 + wr * (AI * 16) + i * 16 + qd * 4;
#pragma unroll
    for (int j = 0; j < 4; ++j) {
      int col = n0 + wc * 64 + j * 16 + ln;
      float bv = bias[col];
      if (trv) {
        // transposed bf16 store: vT[col][row..row+3] as one 8B write
        union { uint2 u2; u16 us[4]; } pk;
#pragma unroll
        for (int r = 0; r < 4; ++r) pk.us[r] = f2b(acc[i][j][r] + bv);
        *(uint2*)&((u16*)Cout)[(size_t)col * MROWS + row] = pk.u2;
      } else {
#pragma unroll
        for (int r = 0; r < 4; ++r) {
          float v = (acc[i][j][r] + bv) * oscale;
          if (RELU) v = fmaxf(v, 0.f);
          size_t off = (size_t)(row + r) * N + col;
          if (RESID) v += resid[off];
          if (OUTBF) ((u16*)Cout)[off] = f2b(v);
          else       ((float*)Cout)[off] = v;
        }
      }
    }
  }
}

template <int TN, int RELU, int RESID, int OUTBF, int DBUF>
__global__ __launch_bounds__(256) void gemm_bt_kernel(const u16* __restrict__ A,
                                                      const u16* __restrict__ Bm,
                                                      const float* __restrict__ bias,
                                                      const float* __restrict__ resid,
                                                      void* __restrict__ Cout,
                                                      int M, int N, int K) {
  const int nx = gridDim.x;
  const int nwg = nx * gridDim.y;
  const int wid = xcd_swz(blockIdx.x + nx * blockIdx.y, nwg);
  gemm_bt_body<TN, RELU, RESID, OUTBF, DBUF>(A, Bm, bias, resid, Cout,
                                             M, N, K,
                                             (wid / nx) * 128, (wid % nx) * TN,
                                             1.0f, 0);
}

// fused QKV on the R9-proven TN=64 triple-buf structure: per proj 512 blocks
// (16 N-tiles x 32 M-tiles), z selects projection; ONE gemm_bt_body call
// site (runtime trv/oscale) -> 72 KB LDS -> 2 blocks/CU (R11 lesson!).
// V (z==2) writes transposed vT; Q (z==0) pre-scaled by 0.25 (ref's bug).
__global__ __launch_bounds__(256) void gemm_qkv_kernel(const u16* __restrict__ A,
                                                       const u16* B0, const u16* B1, const u16* B2,
                                                       const float* c0, const float* c1, const float* c2,
                                                       u16* o0, u16* o1, u16* o2) {
  int z = blockIdx.z;
  const int wid = xcd_swz(blockIdx.x + 16 * blockIdx.y, 512);
  const int m0 = (wid >> 4) * 128, n0 = (wid & 15) * 64;
  const u16* Bm = (z == 0) ? B0 : (z == 1) ? B1 : B2;
  const float* bias = (z == 0) ? c0 : (z == 1) ? c1 : c2;
  u16* Cout = (z == 0) ? o0 : (z == 1) ? o1 : o2;
  const float sc = (z == 0) ? 0.25f : 1.0f;
  gemm_bt_body<64, 0, 0, 1, 1>(A, Bm, bias, nullptr, Cout,
                               MROWS, DIM, DIM, m0, n0, sc, z == 2);
}

// ---------------------------------------------------------------- 256x256 GEMM
// 8-wave (512-thread) 256x256 tile, BK=64, wave tile 128x64 (2M x 4N).
// Exits the 4-wave 2-phase plateau (R6: FFN-1 ~1.7x). Single-barrier
// ping-pong dbuf (128 KB LDS, 1 block/CU of 8 waves) — depth-1 suffices:
// COMPUTE (~2000cy) >> GLL latency.
template <int RELU>
__global__ __launch_bounds__(512, 2) void gemm256_kernel(const u16* __restrict__ A,
                                                         const u16* __restrict__ Bm,
                                                         const float* __restrict__ bias,
                                                         u16* __restrict__ Cout,
                                                         int M, int N, int K) {
  __shared__ __align__(16) u16 As[2][256 * 64];   // 32 KB x2
  __shared__ __align__(16) u16 Bs[2][256 * 64];   // 32 KB x2  (total 128 KB)
  const int tid = threadIdx.x;
  const int lane = tid & 63, w = tid >> 6;        // 8 waves
  const int wr = w >> 2, wc = w & 3;              // 2M x 4N
  const int ln = lane & 15, qd = lane >> 4;

  const int nx = gridDim.x;
  const int nwg = nx * gridDim.y;
  const int wid = xcd_swz(blockIdx.x + nx * blockIdx.y, nwg);
  const int m0 = (wid / nx) * 256, n0 = (wid % nx) * 256;

  f32x4 acc[8][4] = {};

  const int lrow = lane >> 3;
  const int scl  = (lane & 7) ^ lrow;             // swizzled logical chunk
  const u16* Ag = A  + (size_t)(m0 + w * 32 + lrow) * K + scl * 8;
  const u16* Bg = Bm + (size_t)(n0 + w * 32 + lrow) * K + scl * 8;

  const int co0 = ((qd)     ^ (ln & 7)) * 8;
  const int co1 = ((4 + qd) ^ (ln & 7)) * 8;

  auto STAGE = [&](int buf, int k0) {
#pragma unroll
    for (int r = 0; r < 4; ++r) {
      GLL(Ag + (size_t)(r * 8) * K + k0, As[buf] + (w * 4 + r) * 512);
      GLL(Bg + (size_t)(r * 8) * K + k0, Bs[buf] + (w * 4 + r) * 512);
    }
  };

  auto COMPUTE = [&](int buf) {
#pragma unroll
    for (int kk = 0; kk < 2; ++kk) {
      const int co = kk ? co1 : co0;
      bf16x8 af[8], bf[4];
#pragma unroll
      for (int t = 0; t < 8; ++t)
        af[t] = *(const bf16x8*)&As[buf][(wr * 128 + t * 16 + ln) * 64 + co];
#pragma unroll
      for (int t = 0; t < 4; ++t)
        bf[t] = *(const bf16x8*)&Bs[buf][(wc * 64 + t * 16 + ln) * 64 + co];
      __builtin_amdgcn_s_setprio(1);
#pragma unroll
      for (int i = 0; i < 8; ++i)
#pragma unroll
        for (int j = 0; j < 4; ++j)
          acc[i][j] = __builtin_amdgcn_mfma_f32_16x16x32_bf16(af[i], bf[j], acc[i][j], 0, 0, 0);
      __builtin_amdgcn_s_setprio(0);
    }
  };

  const int nk = K >> 6;
  STAGE(0, 0);                         // prologue
  for (int t = 0; t < nk; ++t) {
    const int p = t & 1;
    __syncthreads();                   // buf[p] DMA done; buf[p] readers (t-1) retired
    if (t + 1 < nk) STAGE(1 - p, (t + 1) * 64);
    COMPUTE(p);
  }

#pragma unroll
  for (int i = 0; i < 8; ++i) {
    int row = m0 + wr * 128 + i * 16 + qd * 4;
#pragma unroll
    for (int j = 0; j < 4; ++j) {
      int col = n0 + wc * 64 + j * 16 + ln;
      float bv = bias[col];
#pragma unroll
      for (int r = 0; r < 4; ++r) {
        float v = acc[i][j][r] + bv;
        if (RELU) v = fmaxf(v, 0.f);
        Cout[(size_t)(row + r) * N + col] = f2b(v);
      }
    }
  }
}

// ---------------------------------------------------------------- flash attention
// R9-proven shape: 128 q-rows/block (grid 512), 4 waves x 32 q-rows; KT=64
// ping-pong dbuf via GLL + 16B-granule XOR swizzle; ONE barrier per tile.
// UNSHIFTED softmax (logits bounded). SWAPPED QK^T (S^T = mfma(K,Q));
// P-store = 8 packed 8B writes; Ps swizzled like Ks/Vt; row sums via a
// ones-vector MFMA. XCD swizzle for K/V L2 residency.
// (R10 lesson: QBLK=64 regresses — K/V fragment reads stop amortizing.)
__global__ __launch_bounds__(256, 2) void attn_kernel(const u16* __restrict__ Q,
                                                      const u16* __restrict__ Km,
                                                      const u16* __restrict__ vT,
                                                      u16* __restrict__ O) {
  __shared__ __align__(16) u16 Ks[2][64 * 64];
  __shared__ __align__(16) u16 Vt[2][64 * 64];
  __shared__ __align__(16) u16 Ps[4][32 * 64];

  const int tid = threadIdx.x, lane = tid & 63, w = tid >> 6;
  const int ln = lane & 15, qd = lane >> 4;
  const int flat = blockIdx.x + 16 * (blockIdx.y + 16 * blockIdx.z);
  const int wid = xcd_swz(flat, 512);
  const int qi = wid & 15, head = (wid >> 4) & 15, b = wid >> 8;
  const int wq0 = b * SEQ + qi * 128 + w * 32;
  const int hcol = head * DH;

  bf16x8 qf[2][2];
#pragma unroll
  for (int ti = 0; ti < 2; ++ti)
#pragma unroll
    for (int kk = 0; kk < 2; ++kk)
      qf[ti][kk] = *(const bf16x8*)&Q[(size_t)(wq0 + ti * 16 + ln) * DIM + hcol + kk * 32 + qd * 8];

  union { u16 u[8]; bf16x8 v; } oneu;
#pragma unroll
  for (int e = 0; e < 8; ++e) oneu.u[e] = 0x3F80;
  const bf16x8 vones = oneu.v;

  f32x4 accO[2][4] = {};
  f32x4 accL[2] = {};

  const int srow = lane >> 3;
  const int scl  = (lane & 7) ^ srow;
  const u16* Kg = Km + (size_t)(b * SEQ + w * 16 + srow) * DIM + hcol + scl * 8;
  const u16* Vg = vT + (size_t)(hcol + w * 16 + srow) * MROWS + b * SEQ + scl * 8;
  u16* Pw = Ps[w];
  const int swz = ln & 7;

#pragma unroll
  for (int r = 0; r < 2; ++r) {
    GLL(Kg + (size_t)(r * 8) * DIM,   &Ks[0][(w * 2 + r) * 512]);
    GLL(Vg + (size_t)(r * 8) * MROWS, &Vt[0][(w * 2 + r) * 512]);
  }

  for (int t = 0; t < SEQ / 64; ++t) {
    const int p = t & 1;
    const int kt = t * 64;
    __syncthreads();

    if (t + 1 < SEQ / 64) {
      const int kt2 = kt + 64;
#pragma unroll
      for (int r = 0; r < 2; ++r) {
        GLL(Kg + (size_t)(kt2 + r * 8) * DIM,   &Ks[1 - p][(w * 2 + r) * 512]);
        GLL(Vg + (size_t)(r * 8) * MROWS + kt2, &Vt[1 - p][(w * 2 + r) * 512]);
      }
    }

    f32x4 sacc[4][2] = {};
#pragma unroll
    for (int kk = 0; kk < 2; ++kk) {
      bf16x8 kf[4];
#pragma unroll
      for (int tj = 0; tj < 4; ++tj)
        kf[tj] = *(const bf16x8*)&Ks[p][(tj * 16 + ln) * 64 + (((kk * 4 + qd) ^ swz) * 8)];
      __builtin_amdgcn_s_setprio(1);
#pragma unroll
      for (int tj = 0; tj < 4; ++tj)
#pragma unroll
        for (int ti = 0; ti < 2; ++ti)
          sacc[tj][ti] = __builtin_amdgcn_mfma_f32_16x16x32_bf16(kf[tj], qf[ti][kk], sacc[tj][ti], 0, 0, 0);
      __builtin_amdgcn_s_setprio(0);
    }

#pragma unroll
    for (int tj = 0; tj < 4; ++tj)
#pragma unroll
      for (int ti = 0; ti < 2; ++ti) {
        uint lo = pkbf2(__expf(sacc[tj][ti][0]), __expf(sacc[tj][ti][1]));
        uint hi = pkbf2(__expf(sacc[tj][ti][2]), __expf(sacc[tj][ti][3]));
        *(uint2*)&Pw[(ti * 16 + ln) * 64 + (((2 * tj + (qd >> 1)) ^ swz) * 8) + (qd & 1) * 4] =
            make_uint2(lo, hi);
      }

#pragma unroll
    for (int kk = 0; kk < 2; ++kk) {
      bf16x8 pf[2], vf[4];
#pragma unroll
      for (int ti = 0; ti < 2; ++ti)
        pf[ti] = *(const bf16x8*)&Pw[(ti * 16 + ln) * 64 + (((kk * 4 + qd) ^ swz) * 8)];
#pragma unroll
      for (int tjv = 0; tjv < 4; ++tjv)
        vf[tjv] = *(const bf16x8*)&Vt[p][(tjv * 16 + ln) * 64 + (((kk * 4 + qd) ^ swz) * 8)];
      __builtin_amdgcn_s_setprio(1);
#pragma unroll
      for (int ti = 0; ti < 2; ++ti) {
#pragma unroll
        for (int tjv = 0; tjv < 4; ++tjv)
          accO[ti][tjv] = __builtin_amdgcn_mfma_f32_16x16x32_bf16(pf[ti], vf[tjv], accO[ti][tjv], 0, 0, 0);
        accL[ti] = __builtin_amdgcn_mfma_f32_16x16x32_bf16(pf[ti], vones, accL[ti], 0, 0, 0);
      }
      __builtin_amdgcn_s_setprio(0);
    }
  }

#pragma unroll
  for (int ti = 0; ti < 2; ++ti)
#pragma unroll
    for (int r = 0; r < 4; ++r) {
      float inv = 1.f / accL[ti][r];
#pragma unroll
      for (int tjv = 0; tjv < 4; ++tjv)
        O[(size_t)(wq0 + ti * 16 + qd * 4 + r) * DIM + hcol + tjv * 16 + ln] =
            f2b(accO[ti][tjv][r] * inv);
    }
}

// ---------------------------------------------------------------- launch
extern "C" void kernel_launch(void* const* d_in, const int* in_sizes, int n_in,
                              void* d_out, int out_size, void* d_ws, size_t ws_size,
                              hipStream_t stream) {
  const float* x  = (const float*)d_in[0];
  const float* wq = (const float*)d_in[1];
  const float* bq = (const float*)d_in[2];
  const float* wk = (const float*)d_in[3];
  const float* bk = (const float*)d_in[4];
  const float* wv = (const float*)d_in[5];
  const float* bv = (const float*)d_in[6];
  const float* wo = (const float*)d_in[7];
  const float* bo = (const float*)d_in[8];
  const float* w1 = (const float*)d_in[9];
  const float* b1 = (const float*)d_in[10];
  const float* w2 = (const float*)d_in[11];
  const float* b2 = (const float*)d_in[12];
  float* out = (float*)d_out;
  char* ws = (char*)d_ws;

  const size_t MB = 1u << 20;
  u16*   h    = (u16*)(ws + 0);          // 8 MB (reused as y)
  u16*   q    = (u16*)(ws + 8  * MB);    // 8 MB
  u16*   k    = (u16*)(ws + 16 * MB);    // 8 MB
  u16*   v    = (u16*)(ws + 24 * MB);    // 8 MB  (vT: DIM x MROWS)
  u16*   o    = (u16*)(ws + 32 * MB);    // 8 MB
  u16*   r    = (u16*)(ws + 8  * MB);    // 32 MB, reuses q..o region (after attention done)
  float* ares = (float*)(ws + 40 * MB);  // 16 MB fp32
  u16*   wqb  = (u16*)(ws + 56 * MB);
  u16*   wkb  = (u16*)(ws + 58 * MB);
  u16*   wvb  = (u16*)(ws + 60 * MB);
  u16*   wob  = (u16*)(ws + 62 * MB);
  u16*   w1b  = (u16*)(ws + 64 * MB);    // 8 MB
  u16*   w2b  = (u16*)(ws + 72 * MB);    // 8 MB
  float* stats= (float*)(ws + 80 * MB);  // 8 floats
  u16*   y    = h;

  (void)hipMemsetAsync(stats, 0, 64, stream);

  // weights -> bf16 (2 fused launches)
  cvt4_kernel<<<dim3(512, 4),  256, 0, stream>>>(wq, wk, wv, wo, wqb, wkb, wvb, wob, DIM * DIM);
  cvt4_kernel<<<dim3(2048, 2), 256, 0, stream>>>(w1, w2, w1, w2, w1b, w2b, w1b, w2b, FFD * DIM);

  // LN1
  reduce_stats_kernel<<<dim3(64, 2), 256, 0, stream>>>(x, stats);
  ln_apply_kernel<<<4096, 256, 0, stream>>>(x, stats, h);

  // QKV: TN=64 triple-buf counted-vmcnt, 512 blocks/proj (2 blocks/CU)
  gemm_qkv_kernel<<<dim3(16, 32, 3), 256, 0, stream>>>(h, wqb, wkb, wvb, bq, bk, bv, q, k, v);

  // attention: 128-row q-tiles -> 512 blocks (R9 shape)
  attn_kernel<<<dim3(16, 16, 2), 256, 0, stream>>>(q, k, v, o);

  // out-proj + residual(x) -> ares (fp32); TN=64 triple-buf counted-vmcnt
  gemm_bt_kernel<64, 0, 1, 0, 1><<<dim3(16, 32), 256, 0, stream>>>(o, wob, bo, x, ares, MROWS, DIM, DIM);

  // LN2 (separate reduce pass — R12 lesson: fused per-wave atomics serialize)
  reduce_stats_kernel<<<dim3(64, 2), 256, 0, stream>>>(ares, stats + 4);
  ln_apply_kernel<<<4096, 256, 0, stream>>>(ares, stats + 4, y);

  // FFN-1: 256x256 8-wave kernel, grid 16x16 = 256 blocks (1/CU, 8 waves)
  gemm256_kernel<1><<<dim3(16, 16), 512, 0, stream>>>(y, w1b, b1, r, MROWS, FFD, DIM);

  // FFN-2: TN=64 triple-buf counted-vmcnt, grid 512 (2 blocks/CU)
  gemm_bt_kernel<64, 0, 1, 0, 1><<<dim3(16, 32), 256, 0, stream>>>(r, w2b, b2, x, out, MROWS, DIM, FFD);
}

// Round 14
// 351.173 us; speedup vs baseline: 1.2138x; 1.0169x over previous
//
#include <hip/hip_runtime.h>
#include <cstdint>
#include <cstddef>

typedef unsigned short u16;
typedef unsigned int uint;
typedef __bf16 bf16x8 __attribute__((ext_vector_type(8)));
typedef float f32x4 __attribute__((ext_vector_type(4)));

#define BATCH 2
#define SEQ 2048
#define DIM 1024
#define NH 16
#define DH 64
#define FFD 4096
#define MROWS 4096            // BATCH*SEQ
#define PER_BATCH 2097152     // SEQ*DIM

__device__ __forceinline__ u16 f2b(float f) {
  uint u = __builtin_bit_cast(uint, f);
  u += 0x7FFFu + ((u >> 16) & 1u);   // RNE
  return (u16)(u >> 16);
}

// pack 2 floats -> 2 bf16 in one u32; native casts are RNE (identical to f2b)
__device__ __forceinline__ uint pkbf2(float a, float b) {
  u16 x = __builtin_bit_cast(u16, (__bf16)a);
  u16 y = __builtin_bit_cast(u16, (__bf16)b);
  return (uint)x | ((uint)y << 16);
}

// XCD-aware bijective block swizzle (requires nwg % 8 == 0 — true here).
__device__ __forceinline__ int xcd_swz(int flat, int nwg) {
  return (flat & 7) * (nwg >> 3) + (flat >> 3);
}

// async global->LDS, 16B per lane; LDS dest is wave-uniform base + lane*16
#define GLL(gp, lp)                                                            \
  __builtin_amdgcn_global_load_lds(                                            \
      (const __attribute__((address_space(1))) void*)(gp),                     \
      (__attribute__((address_space(3))) void*)(lp), 16, 0, 0)

// ---------------------------------------------------------------- elementwise
// all 6 weight matrices in ONE launch (4x 1M-elem, 2x 4M-elem; small slices
// early-exit their excess blocks — negligible cost, saves a launch).
__global__ __launch_bounds__(256) void cvt6_kernel(const float* __restrict__ s0,
                                                   const float* __restrict__ s1,
                                                   const float* __restrict__ s2,
                                                   const float* __restrict__ s3,
                                                   const float* __restrict__ s4,
                                                   const float* __restrict__ s5,
                                                   u16* d0, u16* d1, u16* d2,
                                                   u16* d3, u16* d4, u16* d5) {
  int t = blockIdx.y;
  const float* src = (t == 0) ? s0 : (t == 1) ? s1 : (t == 2) ? s2
                   : (t == 3) ? s3 : (t == 4) ? s4 : s5;
  u16* dst = (t == 0) ? d0 : (t == 1) ? d1 : (t == 2) ? d2
           : (t == 3) ? d3 : (t == 4) ? d4 : d5;
  int n = (t < 4) ? DIM * DIM : FFD * DIM;
  int i = (blockIdx.x * 256 + threadIdx.x) * 8;
  if (i >= n) return;
  float4 a = *(const float4*)(src + i);
  float4 b = *(const float4*)(src + i + 4);
  uint4 o;
  o.x = f2b(a.x) | ((uint)f2b(a.y) << 16);
  o.y = f2b(a.z) | ((uint)f2b(a.w) << 16);
  o.z = f2b(b.x) | ((uint)f2b(b.y) << 16);
  o.w = f2b(b.z) | ((uint)f2b(b.w) << 16);
  *(uint4*)(dst + i) = o;
}

__global__ __launch_bounds__(256) void reduce_stats_kernel(const float* __restrict__ x,
                                                           float* __restrict__ stats) {
  int b = blockIdx.y;
  const float* p = x + (size_t)b * PER_BATCH;
  float s = 0.f, ss = 0.f;
  int stride = gridDim.x * 256 * 4;
  for (int i = (blockIdx.x * 256 + threadIdx.x) * 4; i < PER_BATCH; i += stride) {
    float4 v = *(const float4*)(p + i);
    s  += (v.x + v.y) + (v.z + v.w);
    ss += (v.x * v.x + v.y * v.y) + (v.z * v.z + v.w * v.w);
  }
#pragma unroll
  for (int m = 32; m; m >>= 1) { s += __shfl_xor(s, m); ss += __shfl_xor(ss, m); }
  __shared__ float red[16];
  int w = threadIdx.x >> 6;
  if ((threadIdx.x & 63) == 0) { red[w] = s; red[8 + w] = ss; }
  __syncthreads();
  if (threadIdx.x == 0) {
    atomicAdd(&stats[b * 2],     red[0] + red[1] + red[2] + red[3]);
    atomicAdd(&stats[b * 2 + 1], red[8] + red[9] + red[10] + red[11]);
  }
}

__global__ __launch_bounds__(256) void ln_apply_kernel(const float* __restrict__ xin,
                                                       const float* __restrict__ stats,
                                                       u16* __restrict__ out) {
  int i = (blockIdx.x * 256 + threadIdx.x) * 4;
  int b = i >> 21;   // i / PER_BATCH
  const float inv = 1.f / (float)PER_BATCH;
  float mu = stats[b * 2] * inv;
  float var = stats[b * 2 + 1] * inv - mu * mu;
  float rs = rsqrtf(var + 1e-5f);
  float4 v = *(const float4*)(xin + i);
  uint r0 = f2b((v.x - mu) * rs) | ((uint)f2b((v.y - mu) * rs) << 16);
  uint r1 = f2b((v.z - mu) * rs) | ((uint)f2b((v.w - mu) * rs) << 16);
  *(uint2*)(out + i) = make_uint2(r0, r1);
}

// ---------------------------------------------------------------- GEMM (C = A * B^T)
// m97 structure + 16B-granule XOR swizzle on LDS tiles:
//   phys chunk = c_log ^ (row & 7); GLL source chunk scl = (lane&7)^(lane>>3)
//   keeps the DMA lane-linear. Frag-read chunk offset ((kk*4+qd)^(ln&7)) is
//   loop-invariant.
// STRUCTURE LESSONS (R3-R13):
//   - 2-phase 4-wave blocks plateau at MfmaUtil ~22%; TN=64 triple-buf
//     counted vmcnt(6) recovers ~5% (R9). 8-wave 256^2 exits the plateau
//     (R6 FFN-1 ~1.7x) but needs a full grid (R8: 192 blocks neutral).
//   - ATOMIC split-K epilogue NOT viable (R7). Per-wave atomics to one
//     cache line catastrophic (R12: +50us). attn QBLK=64 regressed (R10).
//   - __shared__ is PER TEMPLATE INSTANTIATION (R11: two call sites sum LDS).
//   - QKV: 3 projections share A -> fuse into one block (qkv3): stage A
//     once + 3 B-tiles, 48 MFMA / 10 GLL per K-step (1.8x intensity),
//     3x-long COMPUTE -> depth-1 ping-pong suffices (gemm256 logic).
template <int TN, int RELU, int RESID, int OUTBF, int DBUF>
__device__ __forceinline__ void gemm_bt_body(const u16* __restrict__ A,
                                             const u16* __restrict__ Bm,
                                             const float* __restrict__ bias,
                                             const float* __restrict__ resid,
                                             void* __restrict__ Cout,
                                             int M, int N, int K,
                                             int m0, int n0, float oscale, int trv) {
  constexpr int AI  = (TN == 128) ? 4 : 2;   // 16-row acc tiles per wave
  constexpr int BCH = (TN == 128) ? 4 : 2;   // B staging chunks per wave
  constexpr int NB  = DBUF ? 3 : 1;          // LDS buffers (3 = counted pipeline)
  __shared__ __align__(16) u16 As[NB][128 * 64];
  __shared__ __align__(16) u16 Bs[NB][TN * 64];
  const int tid = threadIdx.x;
  const int lane = tid & 63, w = tid >> 6;
  const int wr = (TN == 128) ? (w >> 1) : w;
  const int wc = (TN == 128) ? (w & 1) : 0;
  const int ln = lane & 15, qd = lane >> 4;

  f32x4 acc[AI][4] = {};

  const int lrow = lane >> 3;
  const int scl  = (lane & 7) ^ lrow;        // swizzled logical chunk
  const u16* Ag = A  + (size_t)(m0 + w * 32 + lrow) * K + scl * 8;
  const u16* Bg = Bm + (size_t)(n0 + w * 8 * BCH + lrow) * K + scl * 8;

  const int co0 = ((qd)     ^ (ln & 7)) * 8;
  const int co1 = ((4 + qd) ^ (ln & 7)) * 8;

  auto STAGE = [&](int buf, int k0) {
#pragma unroll
    for (int r = 0; r < 4; ++r)
      GLL(Ag + (size_t)(r * 8) * K + k0, As[buf] + (w * 4 + r) * 512);
#pragma unroll
    for (int r = 0; r < BCH; ++r)
      GLL(Bg + (size_t)(r * 8) * K + k0, Bs[buf] + (w * BCH + r) * 512);
  };

  auto COMPUTE = [&](int buf) {
#pragma unroll
    for (int kk = 0; kk < 2; ++kk) {
      const int co = kk ? co1 : co0;
      bf16x8 af[AI], bf[4];
#pragma unroll
      for (int t = 0; t < AI; ++t)
        af[t] = *(const bf16x8*)&As[buf][(wr * (AI * 16) + t * 16 + ln) * 64 + co];
#pragma unroll
      for (int t = 0; t < 4; ++t)
        bf[t] = *(const bf16x8*)&Bs[buf][(wc * 64 + t * 16 + ln) * 64 + co];
#pragma unroll
      for (int i = 0; i < AI; ++i)
#pragma unroll
        for (int j = 0; j < 4; ++j)
          acc[i][j] = __builtin_amdgcn_mfma_f32_16x16x32_bf16(af[i], bf[j], acc[i][j], 0, 0, 0);
    }
  };

  if constexpr (NB == 3) {
    // depth-2 counted pipeline: 6 GLLs per wave per STAGE (T4: never drain
    // vmcnt to 0 in the loop). Hazard: buffer (t+2)%3 was last read in
    // COMPUTE(t-1) whose ds_reads retire before any wave passes barrier t.
    const int nk = K >> 6;
    STAGE(0, 0);
    STAGE(1, 64);
    int c = 0, s = 2;
    int t = 0;
    for (; t + 1 < nk; ++t) {
      asm volatile("s_waitcnt vmcnt(6)" ::: "memory");
      __builtin_amdgcn_s_barrier();
      __builtin_amdgcn_sched_barrier(0);
      if (t + 2 < nk) STAGE(s, (t + 2) * 64);
      COMPUTE(c);
      c = (c == 2) ? 0 : c + 1;
      s = (s == 2) ? 0 : s + 1;
    }
    asm volatile("s_waitcnt vmcnt(0)" ::: "memory");
    __builtin_amdgcn_s_barrier();
    __builtin_amdgcn_sched_barrier(0);
    COMPUTE(c);
  } else {
    for (int k0 = 0; k0 < K; k0 += 64) {
      __syncthreads();
      STAGE(0, k0);
      __syncthreads();
      COMPUTE(0);
    }
  }

#pragma unroll
  for (int i = 0; i < AI; ++i) {
    int row = m0 + wr * (AI * 16) + i * 16 + qd * 4;
#pragma unroll
    for (int j = 0; j < 4; ++j) {
      int col = n0 + wc * 64 + j * 16 + ln;
      float bv = bias[col];
      if (trv) {
        // transposed bf16 store: vT[col][row..row+3] as one 8B write
        union { uint2 u2; u16 us[4]; } pk;
#pragma unroll
        for (int r = 0; r < 4; ++r) pk.us[r] = f2b(acc[i][j][r] + bv);
        *(uint2*)&((u16*)Cout)[(size_t)col * MROWS + row] = pk.u2;
      } else {
#pragma unroll
        for (int r = 0; r < 4; ++r) {
          float v = (acc[i][j][r] + bv) * oscale;
          if (RELU) v = fmaxf(v, 0.f);
          size_t off = (size_t)(row + r) * N + col;
          if (RESID) v += resid[off];
          if (OUTBF) ((u16*)Cout)[off] = f2b(v);
          else       ((float*)Cout)[off] = v;
        }
      }
    }
  }
}

template <int TN, int RELU, int RESID, int OUTBF, int DBUF>
__global__ __launch_bounds__(256) void gemm_bt_kernel(const u16* __restrict__ A,
                                                      const u16* __restrict__ Bm,
                                                      const float* __restrict__ bias,
                                                      const float* __restrict__ resid,
                                                      void* __restrict__ Cout,
                                                      int M, int N, int K) {
  const int nx = gridDim.x;
  const int nwg = nx * gridDim.y;
  const int wid = xcd_swz(blockIdx.x + nx * blockIdx.y, nwg);
  gemm_bt_body<TN, RELU, RESID, OUTBF, DBUF>(A, Bm, bias, resid, Cout,
                                             M, N, K,
                                             (wid / nx) * 128, (wid % nx) * TN,
                                             1.0f, 0);
}

// ---------------------------------------------------------------- fused QKV3
// ONE block computes the 128x64 output tile of ALL THREE projections:
// per K-step stage A once (4 GLLs) + 3 B-tiles (6 GLLs), compute 48 MFMAs.
// LDS = 2 x (16KB A + 3x8KB B) = 80 KB exactly -> 2 blocks/CU. Depth-1
// ping-pong: COMPUTE is 3x the TN=64 kernel's -> covers GLL latency
// (gemm256 logic). acc = f32x4[3][2][4] (96 VGPR) + frags ~ 150 < 256.
// Epilogues per z: q (x0.25 bf16), k (bf16), v (transposed vT store).
__global__ __launch_bounds__(256) void gemm_qkv3_kernel(const u16* __restrict__ A,
                                                        const u16* __restrict__ B0,
                                                        const u16* __restrict__ B1,
                                                        const u16* __restrict__ B2,
                                                        const float* __restrict__ c0,
                                                        const float* __restrict__ c1,
                                                        const float* __restrict__ c2,
                                                        u16* o0, u16* o1, u16* o2) {
  __shared__ __align__(16) u16 As[2][128 * 64];      // 32 KB
  __shared__ __align__(16) u16 Bs[2][3][64 * 64];    // 48 KB
  const int tid = threadIdx.x;
  const int lane = tid & 63, w = tid >> 6;
  const int ln = lane & 15, qd = lane >> 4;

  const int wid = xcd_swz(blockIdx.x + 16 * blockIdx.y, 512);
  const int m0 = (wid >> 4) * 128, n0 = (wid & 15) * 64;

  f32x4 acc[3][2][4] = {};

  const int lrow = lane >> 3;
  const int scl  = (lane & 7) ^ lrow;
  const u16* Ag = A + (size_t)(m0 + w * 32 + lrow) * DIM + scl * 8;
  const u16* Bg[3] = {
    B0 + (size_t)(n0 + w * 16 + lrow) * DIM + scl * 8,
    B1 + (size_t)(n0 + w * 16 + lrow) * DIM + scl * 8,
    B2 + (size_t)(n0 + w * 16 + lrow) * DIM + scl * 8 };

  const int co0 = ((qd)     ^ (ln & 7)) * 8;
  const int co1 = ((4 + qd) ^ (ln & 7)) * 8;

  auto STAGE = [&](int buf, int k0) {
#pragma unroll
    for (int r = 0; r < 4; ++r)
      GLL(Ag + (size_t)(r * 8) * DIM + k0, As[buf] + (w * 4 + r) * 512);
#pragma unroll
    for (int z = 0; z < 3; ++z)
#pragma unroll
      for (int r = 0; r < 2; ++r)
        GLL(Bg[z] + (size_t)(r * 8) * DIM + k0, Bs[buf][z] + (w * 2 + r) * 512);
  };

  auto COMPUTE = [&](int buf) {
#pragma unroll
    for (int kk = 0; kk < 2; ++kk) {
      const int co = kk ? co1 : co0;
      bf16x8 af[2];
#pragma unroll
      for (int t = 0; t < 2; ++t)
        af[t] = *(const bf16x8*)&As[buf][(w * 32 + t * 16 + ln) * 64 + co];
#pragma unroll
      for (int z = 0; z < 3; ++z) {
        bf16x8 bf[4];
#pragma unroll
        for (int t = 0; t < 4; ++t)
          bf[t] = *(const bf16x8*)&Bs[buf][z][(t * 16 + ln) * 64 + co];
#pragma unroll
        for (int i = 0; i < 2; ++i)
#pragma unroll
          for (int j = 0; j < 4; ++j)
            acc[z][i][j] = __builtin_amdgcn_mfma_f32_16x16x32_bf16(af[i], bf[j], acc[z][i][j], 0, 0, 0);
      }
    }
  };

  const int nk = DIM >> 6;     // 16
  STAGE(0, 0);
  for (int t = 0; t < nk; ++t) {
    const int p = t & 1;
    __syncthreads();           // buf[p] DMA done; buf[p] readers (t-1) retired
    if (t + 1 < nk) STAGE(1 - p, (t + 1) * 64);
    COMPUTE(p);
  }

#pragma unroll
  for (int z = 0; z < 3; ++z) {
    const float* bias = (z == 0) ? c0 : (z == 1) ? c1 : c2;
    u16* Cout = (z == 0) ? o0 : (z == 1) ? o1 : o2;
    const float sc = (z == 0) ? 0.25f : 1.0f;
#pragma unroll
    for (int i = 0; i < 2; ++i) {
      int row = m0 + w * 32 + i * 16 + qd * 4;
#pragma unroll
      for (int j = 0; j < 4; ++j) {
        int col = n0 + j * 16 + ln;
        float bv = bias[col];
        if (z == 2) {
          union { uint2 u2; u16 us[4]; } pk;
#pragma unroll
          for (int r = 0; r < 4; ++r) pk.us[r] = f2b(acc[z][i][j][r] + bv);
          *(uint2*)&Cout[(size_t)col * MROWS + row] = pk.u2;
        } else {
#pragma unroll
          for (int r = 0; r < 4; ++r)
            Cout[(size_t)(row + r) * DIM + col] = f2b((acc[z][i][j][r] + bv) * sc);
        }
      }
    }
  }
}

// ---------------------------------------------------------------- 256x256 GEMM
// 8-wave (512-thread) 256x256 tile, BK=64, wave tile 128x64 (2M x 4N).
// Exits the 4-wave 2-phase plateau (R6: FFN-1 ~1.7x). Single-barrier
// ping-pong dbuf (128 KB LDS, 1 block/CU of 8 waves) — depth-1 suffices:
// COMPUTE (~2000cy) >> GLL latency.
template <int RELU>
__global__ __launch_bounds__(512, 2) void gemm256_kernel(const u16* __restrict__ A,
                                                         const u16* __restrict__ Bm,
                                                         const float* __restrict__ bias,
                                                         u16* __restrict__ Cout,
                                                         int M, int N, int K) {
  __shared__ __align__(16) u16 As[2][256 * 64];   // 32 KB x2
  __shared__ __align__(16) u16 Bs[2][256 * 64];   // 32 KB x2  (total 128 KB)
  const int tid = threadIdx.x;
  const int lane = tid & 63, w = tid >> 6;        // 8 waves
  const int wr = w >> 2, wc = w & 3;              // 2M x 4N
  const int ln = lane & 15, qd = lane >> 4;

  const int nx = gridDim.x;
  const int nwg = nx * gridDim.y;
  const int wid = xcd_swz(blockIdx.x + nx * blockIdx.y, nwg);
  const int m0 = (wid / nx) * 256, n0 = (wid % nx) * 256;

  f32x4 acc[8][4] = {};

  const int lrow = lane >> 3;
  const int scl  = (lane & 7) ^ lrow;             // swizzled logical chunk
  const u16* Ag = A  + (size_t)(m0 + w * 32 + lrow) * K + scl * 8;
  const u16* Bg = Bm + (size_t)(n0 + w * 32 + lrow) * K + scl * 8;

  const int co0 = ((qd)     ^ (ln & 7)) * 8;
  const int co1 = ((4 + qd) ^ (ln & 7)) * 8;

  auto STAGE = [&](int buf, int k0) {
#pragma unroll
    for (int r = 0; r < 4; ++r) {
      GLL(Ag + (size_t)(r * 8) * K + k0, As[buf] + (w * 4 + r) * 512);
      GLL(Bg + (size_t)(r * 8) * K + k0, Bs[buf] + (w * 4 + r) * 512);
    }
  };

  auto COMPUTE = [&](int buf) {
#pragma unroll
    for (int kk = 0; kk < 2; ++kk) {
      const int co = kk ? co1 : co0;
      bf16x8 af[8], bf[4];
#pragma unroll
      for (int t = 0; t < 8; ++t)
        af[t] = *(const bf16x8*)&As[buf][(wr * 128 + t * 16 + ln) * 64 + co];
#pragma unroll
      for (int t = 0; t < 4; ++t)
        bf[t] = *(const bf16x8*)&Bs[buf][(wc * 64 + t * 16 + ln) * 64 + co];
      __builtin_amdgcn_s_setprio(1);
#pragma unroll
      for (int i = 0; i < 8; ++i)
#pragma unroll
        for (int j = 0; j < 4; ++j)
          acc[i][j] = __builtin_amdgcn_mfma_f32_16x16x32_bf16(af[i], bf[j], acc[i][j], 0, 0, 0);
      __builtin_amdgcn_s_setprio(0);
    }
  };

  const int nk = K >> 6;
  STAGE(0, 0);                         // prologue
  for (int t = 0; t < nk; ++t) {
    const int p = t & 1;
    __syncthreads();                   // buf[p] DMA done; buf[p] readers (t-1) retired
    if (t + 1 < nk) STAGE(1 - p, (t + 1) * 64);
    COMPUTE(p);
  }

#pragma unroll
  for (int i = 0; i < 8; ++i) {
    int row = m0 + wr * 128 + i * 16 + qd * 4;
#pragma unroll
    for (int j = 0; j < 4; ++j) {
      int col = n0 + wc * 64 + j * 16 + ln;
      float bv = bias[col];
#pragma unroll
      for (int r = 0; r < 4; ++r) {
        float v = acc[i][j][r] + bv;
        if (RELU) v = fmaxf(v, 0.f);
        Cout[(size_t)(row + r) * N + col] = f2b(v);
      }
    }
  }
}

// ---------------------------------------------------------------- flash attention
// R9-proven shape: 128 q-rows/block (grid 512), 4 waves x 32 q-rows; KT=64
// ping-pong dbuf via GLL + 16B-granule XOR swizzle; ONE barrier per tile.
// UNSHIFTED softmax (logits bounded). SWAPPED QK^T (S^T = mfma(K,Q));
// P-store = 8 packed 8B writes; Ps swizzled like Ks/Vt; row sums via a
// ones-vector MFMA. XCD swizzle for K/V L2 residency.
// (R10 lesson: QBLK=64 regresses — K/V fragment reads stop amortizing.)
__global__ __launch_bounds__(256, 2) void attn_kernel(const u16* __restrict__ Q,
                                                      const u16* __restrict__ Km,
                                                      const u16* __restrict__ vT,
                                                      u16* __restrict__ O) {
  __shared__ __align__(16) u16 Ks[2][64 * 64];
  __shared__ __align__(16) u16 Vt[2][64 * 64];
  __shared__ __align__(16) u16 Ps[4][32 * 64];

  const int tid = threadIdx.x, lane = tid & 63, w = tid >> 6;
  const int ln = lane & 15, qd = lane >> 4;
  const int flat = blockIdx.x + 16 * (blockIdx.y + 16 * blockIdx.z);
  const int wid = xcd_swz(flat, 512);
  const int qi = wid & 15, head = (wid >> 4) & 15, b = wid >> 8;
  const int wq0 = b * SEQ + qi * 128 + w * 32;
  const int hcol = head * DH;

  bf16x8 qf[2][2];
#pragma unroll
  for (int ti = 0; ti < 2; ++ti)
#pragma unroll
    for (int kk = 0; kk < 2; ++kk)
      qf[ti][kk] = *(const bf16x8*)&Q[(size_t)(wq0 + ti * 16 + ln) * DIM + hcol + kk * 32 + qd * 8];

  union { u16 u[8]; bf16x8 v; } oneu;
#pragma unroll
  for (int e = 0; e < 8; ++e) oneu.u[e] = 0x3F80;
  const bf16x8 vones = oneu.v;

  f32x4 accO[2][4] = {};
  f32x4 accL[2] = {};

  const int srow = lane >> 3;
  const int scl  = (lane & 7) ^ srow;
  const u16* Kg = Km + (size_t)(b * SEQ + w * 16 + srow) * DIM + hcol + scl * 8;
  const u16* Vg = vT + (size_t)(hcol + w * 16 + srow) * MROWS + b * SEQ + scl * 8;
  u16* Pw = Ps[w];
  const int swz = ln & 7;

#pragma unroll
  for (int r = 0; r < 2; ++r) {
    GLL(Kg + (size_t)(r * 8) * DIM,   &Ks[0][(w * 2 + r) * 512]);
    GLL(Vg + (size_t)(r * 8) * MROWS, &Vt[0][(w * 2 + r) * 512]);
  }

  for (int t = 0; t < SEQ / 64; ++t) {
    const int p = t & 1;
    const int kt = t * 64;
    __syncthreads();

    if (t + 1 < SEQ / 64) {
      const int kt2 = kt + 64;
#pragma unroll
      for (int r = 0; r < 2; ++r) {
        GLL(Kg + (size_t)(kt2 + r * 8) * DIM,   &Ks[1 - p][(w * 2 + r) * 512]);
        GLL(Vg + (size_t)(r * 8) * MROWS + kt2, &Vt[1 - p][(w * 2 + r) * 512]);
      }
    }

    f32x4 sacc[4][2] = {};
#pragma unroll
    for (int kk = 0; kk < 2; ++kk) {
      bf16x8 kf[4];
#pragma unroll
      for (int tj = 0; tj < 4; ++tj)
        kf[tj] = *(const bf16x8*)&Ks[p][(tj * 16 + ln) * 64 + (((kk * 4 + qd) ^ swz) * 8)];
      __builtin_amdgcn_s_setprio(1);
#pragma unroll
      for (int tj = 0; tj < 4; ++tj)
#pragma unroll
        for (int ti = 0; ti < 2; ++ti)
          sacc[tj][ti] = __builtin_amdgcn_mfma_f32_16x16x32_bf16(kf[tj], qf[ti][kk], sacc[tj][ti], 0, 0, 0);
      __builtin_amdgcn_s_setprio(0);
    }

#pragma unroll
    for (int tj = 0; tj < 4; ++tj)
#pragma unroll
      for (int ti = 0; ti < 2; ++ti) {
        uint lo = pkbf2(__expf(sacc[tj][ti][0]), __expf(sacc[tj][ti][1]));
        uint hi = pkbf2(__expf(sacc[tj][ti][2]), __expf(sacc[tj][ti][3]));
        *(uint2*)&Pw[(ti * 16 + ln) * 64 + (((2 * tj + (qd >> 1)) ^ swz) * 8) + (qd & 1) * 4] =
            make_uint2(lo, hi);
      }

#pragma unroll
    for (int kk = 0; kk < 2; ++kk) {
      bf16x8 pf[2], vf[4];
#pragma unroll
      for (int ti = 0; ti < 2; ++ti)
        pf[ti] = *(const bf16x8*)&Pw[(ti * 16 + ln) * 64 + (((kk * 4 + qd) ^ swz) * 8)];
#pragma unroll
      for (int tjv = 0; tjv < 4; ++tjv)
        vf[tjv] = *(const bf16x8*)&Vt[p][(tjv * 16 + ln) * 64 + (((kk * 4 + qd) ^ swz) * 8)];
      __builtin_amdgcn_s_setprio(1);
#pragma unroll
      for (int ti = 0; ti < 2; ++ti) {
#pragma unroll
        for (int tjv = 0; tjv < 4; ++tjv)
          accO[ti][tjv] = __builtin_amdgcn_mfma_f32_16x16x32_bf16(pf[ti], vf[tjv], accO[ti][tjv], 0, 0, 0);
        accL[ti] = __builtin_amdgcn_mfma_f32_16x16x32_bf16(pf[ti], vones, accL[ti], 0, 0, 0);
      }
      __builtin_amdgcn_s_setprio(0);
    }
  }

#pragma unroll
  for (int ti = 0; ti < 2; ++ti)
#pragma unroll
    for (int r = 0; r < 4; ++r) {
      float inv = 1.f / accL[ti][r];
#pragma unroll
      for (int tjv = 0; tjv < 4; ++tjv)
        O[(size_t)(wq0 + ti * 16 + qd * 4 + r) * DIM + hcol + tjv * 16 + ln] =
            f2b(accO[ti][tjv][r] * inv);
    }
}

// ---------------------------------------------------------------- launch
extern "C" void kernel_launch(void* const* d_in, const int* in_sizes, int n_in,
                              void* d_out, int out_size, void* d_ws, size_t ws_size,
                              hipStream_t stream) {
  const float* x  = (const float*)d_in[0];
  const float* wq = (const float*)d_in[1];
  const float* bq = (const float*)d_in[2];
  const float* wk = (const float*)d_in[3];
  const float* bk = (const float*)d_in[4];
  const float* wv = (const float*)d_in[5];
  const float* bv = (const float*)d_in[6];
  const float* wo = (const float*)d_in[7];
  const float* bo = (const float*)d_in[8];
  const float* w1 = (const float*)d_in[9];
  const float* b1 = (const float*)d_in[10];
  const float* w2 = (const float*)d_in[11];
  const float* b2 = (const float*)d_in[12];
  float* out = (float*)d_out;
  char* ws = (char*)d_ws;

  const size_t MB = 1u << 20;
  u16*   h    = (u16*)(ws + 0);          // 8 MB (reused as y)
  u16*   q    = (u16*)(ws + 8  * MB);    // 8 MB
  u16*   k    = (u16*)(ws + 16 * MB);    // 8 MB
  u16*   v    = (u16*)(ws + 24 * MB);    // 8 MB  (vT: DIM x MROWS)
  u16*   o    = (u16*)(ws + 32 * MB);    // 8 MB
  u16*   r    = (u16*)(ws + 8  * MB);    // 32 MB, reuses q..o region (after attention done)
  float* ares = (float*)(ws + 40 * MB);  // 16 MB fp32
  u16*   wqb  = (u16*)(ws + 56 * MB);
  u16*   wkb  = (u16*)(ws + 58 * MB);
  u16*   wvb  = (u16*)(ws + 60 * MB);
  u16*   wob  = (u16*)(ws + 62 * MB);
  u16*   w1b  = (u16*)(ws + 64 * MB);    // 8 MB
  u16*   w2b  = (u16*)(ws + 72 * MB);    // 8 MB
  float* stats= (float*)(ws + 80 * MB);  // 8 floats
  u16*   y    = h;

  (void)hipMemsetAsync(stats, 0, 64, stream);

  // all weights -> bf16 in ONE launch
  cvt6_kernel<<<dim3(2048, 6), 256, 0, stream>>>(wq, wk, wv, wo, w1, w2,
                                                 wqb, wkb, wvb, wob, w1b, w2b);

  // LN1
  reduce_stats_kernel<<<dim3(64, 2), 256, 0, stream>>>(x, stats);
  ln_apply_kernel<<<4096, 256, 0, stream>>>(x, stats, h);

  // QKV: fused 3-projection kernel, 512 blocks (2 blocks/CU, 80 KB LDS)
  gemm_qkv3_kernel<<<dim3(16, 32), 256, 0, stream>>>(h, wqb, wkb, wvb, bq, bk, bv, q, k, v);

  // attention: 128-row q-tiles -> 512 blocks (R9 shape)
  attn_kernel<<<dim3(16, 16, 2), 256, 0, stream>>>(q, k, v, o);

  // out-proj + residual(x) -> ares (fp32); TN=64 triple-buf counted-vmcnt
  gemm_bt_kernel<64, 0, 1, 0, 1><<<dim3(16, 32), 256, 0, stream>>>(o, wob, bo, x, ares, MROWS, DIM, DIM);

  // LN2 (separate reduce pass — R12 lesson: fused per-wave atomics serialize)
  reduce_stats_kernel<<<dim3(64, 2), 256, 0, stream>>>(ares, stats + 4);
  ln_apply_kernel<<<4096, 256, 0, stream>>>(ares, stats + 4, y);

  // FFN-1: 256x256 8-wave kernel, grid 16x16 = 256 blocks (1/CU, 8 waves)
  gemm256_kernel<1><<<dim3(16, 16), 512, 0, stream>>>(y, w1b, b1, r, MROWS, FFD, DIM);

  // FFN-2: TN=64 triple-buf counted-vmcnt, grid 512 (2 blocks/CU)
  gemm_bt_kernel<64, 0, 1, 0, 1><<<dim3(16, 32), 256, 0, stream>>>(r, w2b, b2, x, out, MROWS, DIM, FFD);
}